// Round 1
// baseline (6026.309 us; speedup 1.0000x reference)
//
#include <hip/hip_runtime.h>
#include <math.h>

#define MTOT 32768   // B*R
#define DD   512
#define HH   1024
#define NREL 2048

// ---------------- prep kernels: fold weights ----------------

// wvoT[k][n] = W_vo[n][k],  W_vo = o_w @ v_w   (n = out dim, k = in dim)
__global__ void prep_wvoT(const float* __restrict__ vw, const float* __restrict__ ow,
                          float* __restrict__ wvoT) {
  int idx = blockIdx.x * 256 + threadIdx.x;   // 512*512
  int i = idx & 511;   // out dim (fastest -> coalesced write)
  int j = idx >> 9;    // in dim
  float s = 0.f;
  for (int k = 0; k < DD; ++k) s += ow[i * DD + k] * vw[k * DD + j];
  wvoT[j * DD + i] = s;
}

// c[i] = o_b[i] + sum_k o_w[i][k] * v_b[k]
__global__ void prep_cvec(const float* __restrict__ ow, const float* __restrict__ vb,
                          const float* __restrict__ ob, float* __restrict__ c) {
  int i = blockIdx.x * 256 + threadIdx.x;
  if (i < DD) {
    float s = ob[i];
    for (int k = 0; k < DD; ++k) s += ow[i * DD + k] * vb[k];
    c[i] = s;
  }
}

// w1pT[d][j] = w1[j][d] * ln_g[d]   (LN scale folded; transposed for GEMM)
__global__ void prep_w1pT(const float* __restrict__ w1, const float* __restrict__ g,
                          float* __restrict__ w1pT) {
  int idx = blockIdx.x * 256 + threadIdx.x;   // 512*1024
  int j = idx & (HH - 1);
  int d = idx >> 10;
  w1pT[d * HH + j] = w1[j * DD + d] * g[d];
}

// b1p[j] = b1[j] + sum_d w1[j][d] * ln_b[d]   (LN shift folded)
__global__ void prep_b1p(const float* __restrict__ w1, const float* __restrict__ lnb,
                         const float* __restrict__ b1, float* __restrict__ b1p) {
  int j = blockIdx.x * 256 + threadIdx.x;
  if (j < HH) {
    float s = b1[j];
    for (int d = 0; d < DD; ++d) s += w1[j * DD + d] * lnb[d];
    b1p[j] = s;
  }
}

// w2T[k][n] = w2[n][k]
__global__ void prep_w2T(const float* __restrict__ w2, float* __restrict__ w2T) {
  int idx = blockIdx.x * 256 + threadIdx.x;   // 1024*2048
  int n = idx & (NREL - 1);
  int k = idx >> 11;
  w2T[k * NREL + n] = w2[n * HH + k];
}

// ---------------- GEMM1: A = X @ W_vo^T + c  (fp32 tiled) ----------------
// 64x64 tile, BK=16, 256 threads, 4x4 micro-tile. A is chunk-local.
__global__ __launch_bounds__(256) void gemm1(
    const float* __restrict__ X, const float* __restrict__ wvoT,
    const float* __restrict__ c, float* __restrict__ A, int row0) {
  __shared__ float Xs[16][64];   // [k][m]
  __shared__ float Ws[16][64];   // [k][n]
  int t = threadIdx.x;
  int ty = t >> 4, tx = t & 15;
  int m0 = blockIdx.x * 64;      // chunk-local row tile
  int n0 = blockIdx.y * 64;
  int lm = t >> 2, lk = (t & 3) * 4;
  int wk = t >> 4, wn = (t & 15) * 4;
  float acc[4][4] = {};
  for (int k0 = 0; k0 < DD; k0 += 16) {
    __syncthreads();
    float4 xv = *(const float4*)&X[(size_t)(row0 + m0 + lm) * DD + k0 + lk];
    Xs[lk + 0][lm] = xv.x; Xs[lk + 1][lm] = xv.y;
    Xs[lk + 2][lm] = xv.z; Xs[lk + 3][lm] = xv.w;
    *(float4*)&Ws[wk][wn] = *(const float4*)&wvoT[(size_t)(k0 + wk) * DD + n0 + wn];
    __syncthreads();
#pragma unroll
    for (int k = 0; k < 16; ++k) {
      float4 a4 = *(const float4*)&Xs[k][ty * 4];
      float4 b4 = *(const float4*)&Ws[k][tx * 4];
      float av[4] = {a4.x, a4.y, a4.z, a4.w};
      float bv[4] = {b4.x, b4.y, b4.z, b4.w};
#pragma unroll
      for (int i = 0; i < 4; ++i)
#pragma unroll
        for (int j = 0; j < 4; ++j) acc[i][j] += av[i] * bv[j];
    }
  }
  float4 cb = *(const float4*)&c[n0 + tx * 4];
  float cv[4] = {cb.x, cb.y, cb.z, cb.w};
#pragma unroll
  for (int i = 0; i < 4; ++i) {
    float4 o;
    o.x = acc[i][0] + cv[0]; o.y = acc[i][1] + cv[1];
    o.z = acc[i][2] + cv[2]; o.w = acc[i][3] + cv[3];
    *(float4*)&A[(size_t)(m0 + ty * 4 + i) * DD + n0 + tx * 4] = o;
  }
}

// ---------------- build_h: H = relu(LN(A + state) @ w1'^T + b1') ----------------
// 16 rows per block; yaT kept transposed in LDS; weights streamed from L2.
__global__ __launch_bounds__(256) void build_h(
    const float* __restrict__ A, const float* __restrict__ X,
    const float* __restrict__ na, const float* __restrict__ w1pT,
    const float* __restrict__ b1p, float* __restrict__ Hbuf,
    int row0, int step) {
  __shared__ float yaT[DD][20];       // [d][r], 16 rows, pad to 20 (16B-aligned rows)
  __shared__ float redS[16][16], redQ[16][16];
  __shared__ float mu[16], rsd[16];
  int t = threadIdx.x;
  int rblk = blockIdx.x * 16;         // chunk-local
  // load A + state (coalesced), store transposed
  for (int it = 0; it < 32; ++it) {
    int idx = it * 256 + t;
    int d = idx & (DD - 1);
    int r = idx >> 9;
    float v = A[(size_t)(rblk + r) * DD + d];
    v += (step == 0) ? na[d] : X[(size_t)(row0 + rblk + r) * DD + d];
    yaT[d][r] = v;
  }
  __syncthreads();
  // LN stats: 16 threads per row
  {
    int r = t >> 4, l = t & 15;
    float s = 0.f, q = 0.f;
    for (int i = 0; i < 32; ++i) {
      float v = yaT[l + 16 * i][r];
      s += v; q += v * v;
    }
    redS[r][l] = s; redQ[r][l] = q;
  }
  __syncthreads();
  if (t < 16) {
    float s = 0.f, q = 0.f;
    for (int l = 0; l < 16; ++l) { s += redS[t][l]; q += redQ[t][l]; }
    float m = s * (1.f / DD);
    float v = q * (1.f / DD) - m * m;
    mu[t] = m;
    rsd[t] = 1.f / sqrtf(v + 1e-5f);
  }
  __syncthreads();
  for (int it = 0; it < 32; ++it) {
    int idx = it * 256 + t;
    int d = idx & (DD - 1);
    int r = idx >> 9;
    yaT[d][r] = (yaT[d][r] - mu[r]) * rsd[r];
  }
  __syncthreads();
  // GEMM: 16 rows x 1024 cols; ty=rows/4, tx=cols/4 (64 lanes -> 1KB coalesced b-loads)
  int ty = t >> 6;       // 0..3
  int tx = t & 63;       // 0..63
  for (int nt = 0; nt < 4; ++nt) {
    int n0 = nt * 256;
    float acc[4][4] = {};
#pragma unroll 8
    for (int k = 0; k < DD; ++k) {
      float4 a4 = *(const float4*)&yaT[k][ty * 4];
      float4 b4 = *(const float4*)&w1pT[(size_t)k * HH + n0 + tx * 4];
      float av[4] = {a4.x, a4.y, a4.z, a4.w};
      float bv[4] = {b4.x, b4.y, b4.z, b4.w};
#pragma unroll
      for (int i = 0; i < 4; ++i)
#pragma unroll
        for (int j = 0; j < 4; ++j) acc[i][j] += av[i] * bv[j];
    }
    float4 bb = *(const float4*)&b1p[n0 + tx * 4];
    float bv[4] = {bb.x, bb.y, bb.z, bb.w};
#pragma unroll
    for (int i = 0; i < 4; ++i) {
      float4 o;
      o.x = fmaxf(acc[i][0] + bv[0], 0.f);
      o.y = fmaxf(acc[i][1] + bv[1], 0.f);
      o.z = fmaxf(acc[i][2] + bv[2], 0.f);
      o.w = fmaxf(acc[i][3] + bv[3], 0.f);
      *(float4*)&Hbuf[(size_t)(rblk + ty * 4 + i) * HH + n0 + tx * 4] = o;
    }
  }
}

// ---------------- GEMM3 + online softmax-max epilogue ----------------
// logits = H @ w2^T + b2 ; per row: max, first-argmax, sum exp(l - max).
__global__ __launch_bounds__(256) void gemm3_ep(
    const float* __restrict__ Hbuf, const float* __restrict__ w2T,
    const float* __restrict__ b2, float* __restrict__ mbuf,
    float* __restrict__ ibuf, int row0) {
  __shared__ float HsT[16][64];   // [k][m]
  __shared__ float Wst[16][64];   // [k][n]
  __shared__ float redM[64][16], redSm[64][16];
  __shared__ int   redI[64][16];
  __shared__ float rowM[64], rowS[64];
  __shared__ int   rowI[64];
  int t = threadIdx.x;
  int ty = t >> 4, tx = t & 15;
  int m0 = blockIdx.x * 64;       // chunk-local
  if (t < 64) { rowM[t] = -INFINITY; rowS[t] = 0.f; rowI[t] = 0; }
  int lm = t >> 2, lk = (t & 3) * 4;
  int wk = t >> 4, wn = (t & 15) * 4;
  for (int n0 = 0; n0 < NREL; n0 += 64) {
    float acc[4][4] = {};
    for (int k0 = 0; k0 < HH; k0 += 16) {
      __syncthreads();
      float4 hv = *(const float4*)&Hbuf[(size_t)(m0 + lm) * HH + k0 + lk];
      HsT[lk + 0][lm] = hv.x; HsT[lk + 1][lm] = hv.y;
      HsT[lk + 2][lm] = hv.z; HsT[lk + 3][lm] = hv.w;
      *(float4*)&Wst[wk][wn] = *(const float4*)&w2T[(size_t)(k0 + wk) * NREL + n0 + wn];
      __syncthreads();
#pragma unroll
      for (int k = 0; k < 16; ++k) {
        float4 a4 = *(const float4*)&HsT[k][ty * 4];
        float4 b4 = *(const float4*)&Wst[k][tx * 4];
        float av[4] = {a4.x, a4.y, a4.z, a4.w};
        float bv[4] = {b4.x, b4.y, b4.z, b4.w};
#pragma unroll
        for (int i = 0; i < 4; ++i)
#pragma unroll
          for (int j = 0; j < 4; ++j) acc[i][j] += av[i] * bv[j];
      }
    }
    // per-thread online scan over its 4 cols (ascending), per row
    float4 bb = *(const float4*)&b2[n0 + tx * 4];
    float bv[4] = {bb.x, bb.y, bb.z, bb.w};
#pragma unroll
    for (int i = 0; i < 4; ++i) {
      float lmax = -INFINITY, ls = 0.f; int li = 0;
#pragma unroll
      for (int j = 0; j < 4; ++j) {
        float v = acc[i][j] + bv[j];
        if (v > lmax) { ls = ls * __expf(lmax - v) + 1.f; lmax = v; li = n0 + tx * 4 + j; }
        else          { ls += __expf(v - lmax); }
      }
      int r = ty * 4 + i;
      redM[r][tx] = lmax; redSm[r][tx] = ls; redI[r][tx] = li;
    }
    __syncthreads();
    if (t < 64) {
      int r = t;
      float M = redM[r][0], S = redSm[r][0]; int I = redI[r][0];
      for (int x = 1; x < 16; ++x) {   // ascending cols -> first-occurrence ties
        float m2 = redM[r][x], s2 = redSm[r][x]; int i2 = redI[r][x];
        if (m2 > M) { S = S * __expf(M - m2) + s2; M = m2; I = i2; }
        else        { S += s2 * __expf(m2 - M); }
      }
      float RM = rowM[r], RS = rowS[r]; int RI = rowI[r];
      if (M > RM) { RS = RS * __expf(RM - M) + S; RM = M; RI = I; }
      else        { RS += S * __expf(M - RM); }
      rowM[r] = RM; rowS[r] = RS; rowI[r] = RI;
    }
    // hazard to next tile covered by the k-loop's leading __syncthreads
  }
  __syncthreads();
  if (t < 64) {
    int grow = row0 + m0 + t;
    mbuf[grow] = 1.f / rowS[t];          // p_max = 1/sum(exp(l - lmax))
    ibuf[grow] = (float)rowI[t];
  }
}

// ---------------- finalize: scores / indices / lengths ----------------
__global__ void finalize_k(const float* __restrict__ m0b, const float* __restrict__ i0b,
                           const float* __restrict__ m1b, const float* __restrict__ i1b,
                           float* __restrict__ out) {
  int r = blockIdx.x * 256 + threadIdx.x;
  float mm0 = m0b[r], mm1 = m1b[r];
  float fi0 = i0b[r], fi1 = i1b[r];
  bool c0 = (fi0 != 0.f) && (mm0 >= 0.1f);
  bool c1 = c0 && (fi1 != 0.f) && (mm1 >= 0.1f);
  float sc = c0 ? (c1 ? mm0 * mm1 : mm0) : 0.f;
  out[r] = sc;
  out[MTOT + r] = fi0;
  out[2 * MTOT + r] = fi1;
  out[3 * MTOT + r] = (float)((c0 ? 1 : 0) + (c1 ? 1 : 0));
}

// ---------------- host ----------------
extern "C" void kernel_launch(void* const* d_in, const int* in_sizes, int n_in,
                              void* d_out, int out_size, void* d_ws, size_t ws_size,
                              hipStream_t stream) {
  const float* X   = (const float*)d_in[0];
  const float* na  = (const float*)d_in[1];
  const float* vw  = (const float*)d_in[2];
  const float* vb  = (const float*)d_in[3];
  const float* ow  = (const float*)d_in[4];
  const float* ob  = (const float*)d_in[5];
  const float* lng = (const float*)d_in[6];
  const float* lnb = (const float*)d_in[7];
  const float* w1  = (const float*)d_in[8];
  const float* b1  = (const float*)d_in[9];
  const float* w2  = (const float*)d_in[10];
  const float* b2  = (const float*)d_in[11];
  float* out = (float*)d_out;

  float* ws   = (float*)d_ws;
  float* wvoT = ws; ws += 512 * 512;
  float* cvec = ws; ws += 512;
  float* w1pT = ws; ws += 512 * 1024;
  float* b1p  = ws; ws += 1024;
  float* w2T  = ws; ws += 1024 * 2048;
  float* m0b  = ws; ws += MTOT;
  float* i0b  = ws; ws += MTOT;
  float* m1b  = ws; ws += MTOT;
  float* i1b  = ws; ws += MTOT;
  size_t used = (size_t)(ws - (float*)d_ws);
  size_t avail = ws_size / 4;
  size_t remain = avail > used ? avail - used : 0;
  int chunk = (int)(remain / 1536);   // per-row: A 512 + H 1024 floats
  chunk &= ~63;
  if (chunk < 64) chunk = 64;         // last-resort bet; ws should be bigger
  if (chunk > MTOT) chunk = MTOT;
  float* Abuf = ws;
  float* Hbuf = ws + (size_t)chunk * 512;

  prep_wvoT<<<1024, 256, 0, stream>>>(vw, ow, wvoT);
  prep_cvec<<<2, 256, 0, stream>>>(ow, vb, ob, cvec);
  prep_w1pT<<<2048, 256, 0, stream>>>(w1, lng, w1pT);
  prep_b1p<<<4, 256, 0, stream>>>(w1, lnb, b1, b1p);
  prep_w2T<<<8192, 256, 0, stream>>>(w2, w2T);

  for (int row0 = 0; row0 < MTOT; row0 += chunk) {
    int rows = (MTOT - row0 < chunk) ? (MTOT - row0) : chunk;
    gemm1<<<dim3(rows / 64, 8), 256, 0, stream>>>(X, wvoT, cvec, Abuf, row0);
    for (int s = 0; s < 2; ++s) {
      build_h<<<rows / 16, 256, 0, stream>>>(Abuf, X, na, w1pT, b1p, Hbuf, row0, s);
      gemm3_ep<<<rows / 64, 256, 0, stream>>>(Hbuf, w2T, b2,
          s == 0 ? m0b : m1b, s == 0 ? i0b : i1b, row0);
    }
  }
  finalize_k<<<MTOT / 256, 256, 0, stream>>>(m0b, i0b, m1b, i1b, out);
}

// Round 2
// 1700.195 us; speedup vs baseline: 3.5445x; 3.5445x over previous
//
#include <hip/hip_runtime.h>
#include <math.h>

#define MTOT 32768   // B*R
#define DD   512
#define HHD  1024
#define NRELN 2048
#define SCA  64.f          // A-side (activation) fp16 pre-scale: keeps lo terms normal
#define SCB  1024.f        // B-side (weight) fp16 pre-scale
#define INVS (1.f / 65536.f)

typedef _Float16 h8 __attribute__((ext_vector_type(8)));
typedef float    f4 __attribute__((ext_vector_type(4)));

__device__ inline void fsplit(float x, _Float16& h, _Float16& l) {
  _Float16 t = (_Float16)x;
  h = t;
  l = (_Float16)(x - (float)t);   // exact residual, then rounded: 2^-22 rel total
}

// online softmax-max merge; tie -> min index == numpy first-occurrence (order-free)
__device__ inline void omerge(float& M, float& S, int& I, float m2, float s2, int i2) {
  if (m2 > M || (m2 == M && i2 < I)) { S = S * __expf(M - m2) + s2; M = m2; I = i2; }
  else                               { S += s2 * __expf(m2 - M); }
}

// ---------------- prep: fold + scale + split weights ----------------

// Wvo[n][k] = sum_j o_w[n][j] v_w[j][k]; store fp16 split of Wvo*SCB, layout [n][k]
__global__ void prep_wvo_split(const float* __restrict__ vw, const float* __restrict__ ow,
                               _Float16* __restrict__ wh, _Float16* __restrict__ wl) {
  int idx = blockIdx.x * 256 + threadIdx.x;   // 512*512
  int k = idx & 511;
  int n = idx >> 9;
  float s = 0.f;
  for (int j = 0; j < DD; ++j) s += ow[n * DD + j] * vw[j * DD + k];
  fsplit(s * SCB, wh[n * DD + k], wl[n * DD + k]);
}

// cvec[i] = o_b[i] + sum_k o_w[i][k] v_b[k]   (fp32)
__global__ void prep_cvec(const float* __restrict__ ow, const float* __restrict__ vb,
                          const float* __restrict__ ob, float* __restrict__ c) {
  int i = blockIdx.x * 256 + threadIdx.x;
  if (i < DD) {
    float s = ob[i];
    for (int k = 0; k < DD; ++k) s += ow[i * DD + k] * vb[k];
    c[i] = s;
  }
}

// w1p[n][k] = w1[n][k]*ln_g[k]*SCB, split
__global__ void prep_w1p_split(const float* __restrict__ w1, const float* __restrict__ g,
                               _Float16* __restrict__ wh, _Float16* __restrict__ wl) {
  int idx = blockIdx.x * 256 + threadIdx.x;   // 1024*512
  int k = idx & 511;
  int n = idx >> 9;
  fsplit(w1[n * DD + k] * g[k] * SCB, wh[n * DD + k], wl[n * DD + k]);
}

// b1p[n] = b1[n] + sum_k w1[n][k]*ln_b[k]   (fp32)
__global__ void prep_b1p(const float* __restrict__ w1, const float* __restrict__ lnb,
                         const float* __restrict__ b1, float* __restrict__ b1p) {
  int n = blockIdx.x * 256 + threadIdx.x;
  if (n < HHD) {
    float s = b1[n];
    for (int k = 0; k < DD; ++k) s += w1[n * DD + k] * lnb[k];
    b1p[n] = s;
  }
}

// w2 split: [n][k] already; *SCB
__global__ void prep_w2_split(const float* __restrict__ w2,
                              _Float16* __restrict__ wh, _Float16* __restrict__ wl) {
  int idx = blockIdx.x * 256 + threadIdx.x;   // 2048*1024
  int k = idx & 1023;
  int n = idx >> 10;
  fsplit(w2[n * HHD + k] * SCB, wh[n * HHD + k], wl[n * HHD + k]);
}

// split a chunk of X (fp32 -> fp16 hi/lo, *SCA); 8 elems/thread
__global__ void split_x(const float* __restrict__ src, _Float16* __restrict__ h,
                        _Float16* __restrict__ l) {
  int idx = (blockIdx.x * 256 + threadIdx.x) * 8;
  float4 a = *(const float4*)(src + idx);
  float4 b = *(const float4*)(src + idx + 4);
  float vv[8] = {a.x, a.y, a.z, a.w, b.x, b.y, b.z, b.w};
  _Float16 hh[8], ll[8];
#pragma unroll
  for (int i = 0; i < 8; ++i) fsplit(vv[i] * SCA, hh[i], ll[i]);
  *(h8*)(h + idx) = *(h8*)hh;
  *(h8*)(l + idx) = *(h8*)ll;
}

// ---------------- generic fp16-split MFMA GEMM, 128x128 tile, BK=32 ----------------
// A: [m][K] hi/lo (chunk-local rows), B: [n][K] hi/lo. 256 thr = 4 waves (2x2),
// each wave 4x4 frags of 16x16x32. MODE 0: +cvec -> fp32 A. MODE 1: +b1p, relu,
// *SCA, split -> H. MODE 2: +b2, online max/argmax/sumexp -> partials per col-slot.
template <int MODE, int KDIM, int NTOT>
__global__ __launch_bounds__(256) void gemm_split(
    const _Float16* __restrict__ Ah, const _Float16* __restrict__ Al,
    const _Float16* __restrict__ Bh, const _Float16* __restrict__ Bl,
    const float* __restrict__ bias,
    float* __restrict__ outF,
    _Float16* __restrict__ outHh, _Float16* __restrict__ outHl,
    float* __restrict__ pM, float* __restrict__ pS, float* __restrict__ pI,
    int row0) {
  __shared__ __align__(16) _Float16 sA[2][128][40];   // pad 40: ~2-way banks (free)
  __shared__ __align__(16) _Float16 sB[2][128][40];
  const int t = threadIdx.x;
  const int lane = t & 63;
  const int wv = t >> 6;
  const int wr = wv & 1, wc = wv >> 1;
  const int q = lane >> 4, l16 = lane & 15;
  const int m0 = blockIdx.x << 7;
  const int n0 = blockIdx.y << 7;
  f4 acc[4][4];
#pragma unroll
  for (int i = 0; i < 4; ++i)
#pragma unroll
    for (int j = 0; j < 4; ++j) {
      acc[i][j].x = 0.f; acc[i][j].y = 0.f; acc[i][j].z = 0.f; acc[i][j].w = 0.f;
    }
  for (int k0 = 0; k0 < KDIM; k0 += 32) {
    __syncthreads();
    // stage 2048 16B chunks: arr = it>>1 (Ah,Al,Bh,Bl) -- branch-free after unroll
#pragma unroll
    for (int it = 0; it < 8; ++it) {
      const int arr = it >> 1;
      const int row = ((it & 1) << 6) | (t >> 2);
      const int kc = (t & 3) << 3;
      const _Float16* sp = (arr == 0) ? Ah : (arr == 1) ? Al : (arr == 2) ? Bh : Bl;
      const int base = (arr < 2) ? m0 : n0;
      h8 v = *(const h8*)(sp + (size_t)(base + row) * KDIM + (k0 + kc));
      _Float16* dp = (arr == 0) ? &sA[0][0][0] : (arr == 1) ? &sA[1][0][0]
                   : (arr == 2) ? &sB[0][0][0] : &sB[1][0][0];
      *(h8*)(dp + row * 40 + kc) = v;
    }
    __syncthreads();
    // A-frags: A[m=lane&15][k=q*8+j]  (guide m120); B-frags: B^T rows (n,k-contig)
    h8 afh[4], afl[4];
#pragma unroll
    for (int i = 0; i < 4; ++i) {
      const int ar = (wr << 6) + (i << 4) + l16;
      afh[i] = *(const h8*)&sA[0][ar][q << 3];
      afl[i] = *(const h8*)&sA[1][ar][q << 3];
    }
#pragma unroll
    for (int j = 0; j < 4; ++j) {
      const int br = (wc << 6) + (j << 4) + l16;
      h8 bh = *(const h8*)&sB[0][br][q << 3];
      h8 bl = *(const h8*)&sB[1][br][q << 3];
#pragma unroll
      for (int i = 0; i < 4; ++i) {
        acc[i][j] = __builtin_amdgcn_mfma_f32_16x16x32_f16(afh[i], bh, acc[i][j], 0, 0, 0);
        acc[i][j] = __builtin_amdgcn_mfma_f32_16x16x32_f16(afh[i], bl, acc[i][j], 0, 0, 0);
        acc[i][j] = __builtin_amdgcn_mfma_f32_16x16x32_f16(afl[i], bh, acc[i][j], 0, 0, 0);
      }
    }
  }
  // epilogue; C/D layout: row = q*4+reg, col = lane&15 (guide m89/m91)
  int gcol[4];
  float bb[4];
#pragma unroll
  for (int j = 0; j < 4; ++j) {
    gcol[j] = n0 + (wc << 6) + (j << 4) + l16;
    bb[j] = bias[gcol[j]];
  }
  if constexpr (MODE == 0) {
#pragma unroll
    for (int i = 0; i < 4; ++i)
#pragma unroll
      for (int rr = 0; rr < 4; ++rr) {
        const int rowt = (wr << 6) + (i << 4) + (q << 2) + rr;
#pragma unroll
        for (int j = 0; j < 4; ++j)
          outF[(size_t)(m0 + rowt) * NTOT + gcol[j]] = acc[i][j][rr] * INVS + bb[j];
      }
  } else if constexpr (MODE == 1) {
#pragma unroll
    for (int i = 0; i < 4; ++i)
#pragma unroll
      for (int rr = 0; rr < 4; ++rr) {
        const int rowt = (wr << 6) + (i << 4) + (q << 2) + rr;
#pragma unroll
        for (int j = 0; j < 4; ++j) {
          float v = fmaxf(acc[i][j][rr] * INVS + bb[j], 0.f) * SCA;
          _Float16 hh, ll;
          fsplit(v, hh, ll);
          outHh[(size_t)(m0 + rowt) * NTOT + gcol[j]] = hh;
          outHl[(size_t)(m0 + rowt) * NTOT + gcol[j]] = ll;
        }
      }
  } else {
    const int slot = blockIdx.y * 2 + wc;   // 32 col-slots of 64
#pragma unroll
    for (int i = 0; i < 4; ++i)
#pragma unroll
      for (int rr = 0; rr < 4; ++rr) {
        float v0 = acc[i][0][rr] * INVS + bb[0];
        float M = v0, S = 1.f;
        int I = gcol[0];
#pragma unroll
        for (int j = 1; j < 4; ++j) {
          float v = acc[i][j][rr] * INVS + bb[j];
          omerge(M, S, I, v, 1.f, gcol[j]);
        }
#pragma unroll
        for (int m = 1; m <= 8; m <<= 1) {   // reduce the 16 col-interleaved lanes
          float M2 = __shfl_xor(M, m);
          float S2 = __shfl_xor(S, m);
          int   I2 = __shfl_xor(I, m);
          omerge(M, S, I, M2, S2, I2);
        }
        if (l16 == 0) {
          const int grow = row0 + m0 + (wr << 6) + (i << 4) + (q << 2) + rr;
          pM[(size_t)slot * MTOT + grow] = M;
          pS[(size_t)slot * MTOT + grow] = S;
          pI[(size_t)slot * MTOT + grow] = (float)I;
        }
      }
  }
}

// ---------------- LN + scale + split: y = LN(A + state), store y*SCA hi/lo ----------------
__global__ __launch_bounds__(256) void ln_split(
    const float* __restrict__ A, const float* __restrict__ X,
    const float* __restrict__ na, _Float16* __restrict__ yh,
    _Float16* __restrict__ yl, int row0, int step) {
  int t = threadIdx.x;
  int lane = t & 63;
  int w = t >> 6;
  int r = blockIdx.x * 4 + w;          // chunk-local row, one wave per row
  const float* ap = A + (size_t)r * DD + lane * 8;
  const float* sp = step ? (X + (size_t)(row0 + r) * DD + lane * 8) : (na + lane * 8);
  float v[8];
  float s = 0.f, qq = 0.f;
#pragma unroll
  for (int i = 0; i < 8; ++i) {
    v[i] = ap[i] + sp[i];
    s += v[i];
    qq += v[i] * v[i];
  }
#pragma unroll
  for (int m = 1; m <= 32; m <<= 1) {
    s  += __shfl_xor(s, m);
    qq += __shfl_xor(qq, m);
  }
  float mu = s * (1.f / DD);
  float var = qq * (1.f / DD) - mu * mu;
  float rsd = 1.f / sqrtf(var + 1e-5f);
  _Float16 hh[8], ll[8];
#pragma unroll
  for (int i = 0; i < 8; ++i) fsplit((v[i] - mu) * rsd * SCA, hh[i], ll[i]);
  *(h8*)(yh + (size_t)r * DD + lane * 8) = *(h8*)hh;
  *(h8*)(yl + (size_t)r * DD + lane * 8) = *(h8*)ll;
}

// ---------------- finalize: merge 32 partial slots per step, emit outputs ----------------
__global__ void finalize_k(const float* __restrict__ pM0, const float* __restrict__ pS0,
                           const float* __restrict__ pI0, const float* __restrict__ pM1,
                           const float* __restrict__ pS1, const float* __restrict__ pI1,
                           float* __restrict__ out) {
  int r = blockIdx.x * 256 + threadIdx.x;
  float M = pM0[r], S = pS0[r];
  int I = (int)pI0[r];
  for (int s = 1; s < 32; ++s) {
    size_t o = (size_t)s * MTOT + r;
    omerge(M, S, I, pM0[o], pS0[o], (int)pI0[o]);
  }
  float m0v = 1.f / S;
  int i0v = I;
  M = pM1[r]; S = pS1[r]; I = (int)pI1[r];
  for (int s = 1; s < 32; ++s) {
    size_t o = (size_t)s * MTOT + r;
    omerge(M, S, I, pM1[o], pS1[o], (int)pI1[o]);
  }
  float m1v = 1.f / S;
  int i1v = I;
  bool c0 = (i0v != 0) && (m0v >= 0.1f);
  bool c1 = c0 && (i1v != 0) && (m1v >= 0.1f);
  out[r] = c0 ? (c1 ? m0v * m1v : m0v) : 0.f;
  out[MTOT + r] = (float)i0v;
  out[2 * MTOT + r] = (float)i1v;
  out[3 * MTOT + r] = (float)((c0 ? 1 : 0) + (c1 ? 1 : 0));
}

// ---------------- host ----------------
extern "C" void kernel_launch(void* const* d_in, const int* in_sizes, int n_in,
                              void* d_out, int out_size, void* d_ws, size_t ws_size,
                              hipStream_t stream) {
  const float* X   = (const float*)d_in[0];
  const float* na  = (const float*)d_in[1];
  const float* vw  = (const float*)d_in[2];
  const float* vb  = (const float*)d_in[3];
  const float* ow  = (const float*)d_in[4];
  const float* ob  = (const float*)d_in[5];
  const float* lng = (const float*)d_in[6];
  const float* lnb = (const float*)d_in[7];
  const float* w1  = (const float*)d_in[8];
  const float* b1  = (const float*)d_in[9];
  const float* w2  = (const float*)d_in[10];
  const float* b2  = (const float*)d_in[11];
  float* out = (float*)d_out;

  char* p = (char*)d_ws;
  auto alloc = [&](size_t bytes) -> void* {
    void* r = (void*)p;
    p += (bytes + 255) & ~(size_t)255;
    return r;
  };
  _Float16* wvo_h = (_Float16*)alloc(512 * 512 * 2);
  _Float16* wvo_l = (_Float16*)alloc(512 * 512 * 2);
  float*    cvec  = (float*)alloc(512 * 4);
  _Float16* w1p_h = (_Float16*)alloc(1024 * 512 * 2);
  _Float16* w1p_l = (_Float16*)alloc(1024 * 512 * 2);
  float*    b1p   = (float*)alloc(1024 * 4);
  _Float16* w2_h  = (_Float16*)alloc(2048 * 1024 * 2);
  _Float16* w2_l  = (_Float16*)alloc(2048 * 1024 * 2);
  float* pM0 = (float*)alloc((size_t)32 * MTOT * 4);
  float* pS0 = (float*)alloc((size_t)32 * MTOT * 4);
  float* pI0 = (float*)alloc((size_t)32 * MTOT * 4);
  float* pM1 = (float*)alloc((size_t)32 * MTOT * 4);
  float* pS1 = (float*)alloc((size_t)32 * MTOT * 4);
  float* pI1 = (float*)alloc((size_t)32 * MTOT * 4);
  size_t fixed = (size_t)(p - (char*)d_ws);
  size_t remain = ws_size > fixed + 8192 ? ws_size - fixed - 8192 : 0;
  // per-row bytes: Xsplit 2048 + A 2048 + ysplit 2048 + Hsplit 4096 = 10240
  int chunk = (int)(remain / 10240);
  chunk &= ~127;
  if (chunk < 128) chunk = 128;
  if (chunk > MTOT) chunk = MTOT;
  _Float16* xs_h = (_Float16*)alloc((size_t)chunk * 512 * 2);
  _Float16* xs_l = (_Float16*)alloc((size_t)chunk * 512 * 2);
  float*    Abuf = (float*)alloc((size_t)chunk * 512 * 4);
  _Float16* y_h  = (_Float16*)alloc((size_t)chunk * 512 * 2);
  _Float16* y_l  = (_Float16*)alloc((size_t)chunk * 512 * 2);
  _Float16* H_h  = (_Float16*)alloc((size_t)chunk * 1024 * 2);
  _Float16* H_l  = (_Float16*)alloc((size_t)chunk * 1024 * 2);

  prep_wvo_split<<<1024, 256, 0, stream>>>(vw, ow, wvo_h, wvo_l);
  prep_cvec<<<2, 256, 0, stream>>>(ow, vb, ob, cvec);
  prep_w1p_split<<<2048, 256, 0, stream>>>(w1, lng, w1p_h, w1p_l);
  prep_b1p<<<4, 256, 0, stream>>>(w1, lnb, b1, b1p);
  prep_w2_split<<<8192, 256, 0, stream>>>(w2, w2_h, w2_l);

  for (int row0 = 0; row0 < MTOT; row0 += chunk) {
    int rows = (MTOT - row0 < chunk) ? (MTOT - row0) : chunk;
    split_x<<<rows / 4, 256, 0, stream>>>(X + (size_t)row0 * 512, xs_h, xs_l);
    gemm_split<0, 512, 512><<<dim3(rows / 128, 4), 256, 0, stream>>>(
        xs_h, xs_l, wvo_h, wvo_l, cvec, Abuf, nullptr, nullptr,
        nullptr, nullptr, nullptr, 0);
    for (int s = 0; s < 2; ++s) {
      ln_split<<<rows / 4, 256, 0, stream>>>(Abuf, X, na, y_h, y_l, row0, s);
      gemm_split<1, 512, 1024><<<dim3(rows / 128, 8), 256, 0, stream>>>(
          y_h, y_l, w1p_h, w1p_l, b1p, nullptr, H_h, H_l,
          nullptr, nullptr, nullptr, 0);
      gemm_split<2, 1024, 2048><<<dim3(rows / 128, 16), 256, 0, stream>>>(
          H_h, H_l, w2_h, w2_l, b2, nullptr, nullptr, nullptr,
          s == 0 ? pM0 : pM1, s == 0 ? pS0 : pS1, s == 0 ? pI0 : pI1, row0);
    }
  }
  finalize_k<<<MTOT / 256, 256, 0, stream>>>(pM0, pS0, pI0, pM1, pS1, pI1, out);
}

// Round 3
// 1680.307 us; speedup vs baseline: 3.5864x; 1.0118x over previous
//
#include <hip/hip_runtime.h>
#include <math.h>

#define MTOT 32768   // B*R
#define DD   512
#define HHD  1024
#define NRELN 2048
#define SCA  64.f          // activation fp16 pre-scale (keeps lo terms normal)
#define SCB  1024.f        // weight fp16 pre-scale
#define INVS (1.f / 65536.f)

typedef _Float16 h8  __attribute__((ext_vector_type(8)));
typedef float    f16v __attribute__((ext_vector_type(16)));

__device__ __forceinline__ void fsplit(float x, _Float16& h, _Float16& l) {
  _Float16 t = (_Float16)x;
  h = t;
  l = (_Float16)(x - (float)t);   // hi/lo split: 2^-22 rel error total
}

__device__ __forceinline__ void omerge(float& M, float& S, int& I, float m2, float s2, int i2) {
  if (m2 > M || (m2 == M && i2 < I)) { S = S * __expf(M - m2) + s2; M = m2; I = i2; }
  else                               { S += s2 * __expf(m2 - M); }
}

__device__ __forceinline__ void gld16(const _Float16* g, _Float16* l) {
  __builtin_amdgcn_global_load_lds(
      (const __attribute__((address_space(1))) void*)g,
      (__attribute__((address_space(3))) void*)l, 16, 0, 0);
}

// ---------------- prep: fold + scale + split weights ----------------

__global__ void prep_wvo_split(const float* __restrict__ vw, const float* __restrict__ ow,
                               _Float16* __restrict__ wh, _Float16* __restrict__ wl) {
  int idx = blockIdx.x * 256 + threadIdx.x;   // 512*512
  int k = idx & 511;
  int n = idx >> 9;
  float s = 0.f;
  for (int j = 0; j < DD; ++j) s += ow[n * DD + j] * vw[j * DD + k];
  fsplit(s * SCB, wh[n * DD + k], wl[n * DD + k]);
}

__global__ void prep_cvec(const float* __restrict__ ow, const float* __restrict__ vb,
                          const float* __restrict__ ob, float* __restrict__ c) {
  int i = blockIdx.x * 256 + threadIdx.x;
  if (i < DD) {
    float s = ob[i];
    for (int k = 0; k < DD; ++k) s += ow[i * DD + k] * vb[k];
    c[i] = s;
  }
}

__global__ void prep_w1p_split(const float* __restrict__ w1, const float* __restrict__ g,
                               _Float16* __restrict__ wh, _Float16* __restrict__ wl) {
  int idx = blockIdx.x * 256 + threadIdx.x;   // 1024*512
  int k = idx & 511;
  int n = idx >> 9;
  fsplit(w1[n * DD + k] * g[k] * SCB, wh[n * DD + k], wl[n * DD + k]);
}

__global__ void prep_b1p(const float* __restrict__ w1, const float* __restrict__ lnb,
                         const float* __restrict__ b1, float* __restrict__ b1p) {
  int n = blockIdx.x * 256 + threadIdx.x;
  if (n < HHD) {
    float s = b1[n];
    for (int k = 0; k < DD; ++k) s += w1[n * DD + k] * lnb[k];
    b1p[n] = s;
  }
}

__global__ void prep_w2_split(const float* __restrict__ w2,
                              _Float16* __restrict__ wh, _Float16* __restrict__ wl) {
  int idx = blockIdx.x * 256 + threadIdx.x;   // 2048*1024
  int k = idx & 1023;
  int n = idx >> 10;
  fsplit(w2[n * HHD + k] * SCB, wh[n * HHD + k], wl[n * HHD + k]);
}

__global__ void split_x(const float* __restrict__ src, _Float16* __restrict__ h,
                        _Float16* __restrict__ l) {
  int idx = (blockIdx.x * 256 + threadIdx.x) * 8;
  float4 a = *(const float4*)(src + idx);
  float4 b = *(const float4*)(src + idx + 4);
  float vv[8] = {a.x, a.y, a.z, a.w, b.x, b.y, b.z, b.w};
  _Float16 hh[8], ll[8];
#pragma unroll
  for (int i = 0; i < 8; ++i) fsplit(vv[i] * SCA, hh[i], ll[i]);
  *(h8*)(h + idx) = *(h8*)hh;
  *(h8*)(l + idx) = *(h8*)ll;
}

// ---------------- fp16-split MFMA GEMM, 128x128 tile, BK=32, 32x32x16 core ----
// LDS staged via global_load_lds (wave w stages array w), XOR chunk swizzle:
// 16B chunk c of row r lives at position c ^ ((r>>1)&3).  4 waves 2x2, each
// 64x64 via 2x2 frags of 32x32x16, 3-product hi/lo split.
template <int MODE, int KDIM, int NTOT>
__global__ __launch_bounds__(256) void gemm_split(
    const _Float16* __restrict__ Ah, const _Float16* __restrict__ Al,
    const _Float16* __restrict__ Bh, const _Float16* __restrict__ Bl,
    const float* __restrict__ bias,
    float* __restrict__ outF,
    _Float16* __restrict__ outHh, _Float16* __restrict__ outHl,
    float* __restrict__ pM, float* __restrict__ pS, float* __restrict__ pI,
    int row0) {
  __shared__ __align__(16) _Float16 sA[2][128][32];
  __shared__ __align__(16) _Float16 sB[2][128][32];
  const int t = threadIdx.x;
  const int lane = t & 63;
  const int wv = t >> 6;
  const int wr = wv & 1, wc = wv >> 1;
  const int l31 = lane & 31, half = lane >> 5;
  const int m0 = blockIdx.x << 7;
  const int n0 = blockIdx.y << 7;

  // staging: wave wv owns one of {Ah, Al, Bh, Bl}
  const _Float16* gsp = (wv == 0) ? Ah : (wv == 1) ? Al : (wv == 2) ? Bh : Bl;
  const int gb = (wv < 2) ? m0 : n0;
  _Float16* lbase = (wv == 0) ? &sA[0][0][0] : (wv == 1) ? &sA[1][0][0]
                  : (wv == 2) ? &sB[0][0][0] : &sB[1][0][0];
  const int srow = lane >> 2;                       // 0..15 within 16-row region
  const int schunk = (lane & 3) ^ ((lane >> 3) & 3);  // swizzled source chunk
  const _Float16* gptr0 = gsp + (size_t)(gb + srow) * KDIM + schunk * 8;

  f16v acc[2][2] = {};
  const int swz = (lane >> 1) & 3;                  // ((row&31)>>1)&3

  for (int k0 = 0; k0 < KDIM; k0 += 32) {
    __syncthreads();
#pragma unroll
    for (int it = 0; it < 8; ++it)
      gld16(gptr0 + k0 + (size_t)(it * 16) * KDIM, lbase + it * 512);
    __syncthreads();
#pragma unroll
    for (int ks = 0; ks < 2; ++ks) {
      const int pos = (((ks << 1) + half) ^ swz) << 3;
      h8 af_h[2], af_l[2], bf_h[2], bf_l[2];
#pragma unroll
      for (int i = 0; i < 2; ++i) {
        const int mr = wr * 64 + i * 32 + l31;
        af_h[i] = *(const h8*)&sA[0][mr][pos];
        af_l[i] = *(const h8*)&sA[1][mr][pos];
      }
#pragma unroll
      for (int j = 0; j < 2; ++j) {
        const int nr = wc * 64 + j * 32 + l31;
        bf_h[j] = *(const h8*)&sB[0][nr][pos];
        bf_l[j] = *(const h8*)&sB[1][nr][pos];
      }
#pragma unroll
      for (int j = 0; j < 2; ++j)
#pragma unroll
        for (int i = 0; i < 2; ++i) {
          acc[i][j] = __builtin_amdgcn_mfma_f32_32x32x16_f16(af_h[i], bf_h[j], acc[i][j], 0, 0, 0);
          acc[i][j] = __builtin_amdgcn_mfma_f32_32x32x16_f16(af_h[i], bf_l[j], acc[i][j], 0, 0, 0);
          acc[i][j] = __builtin_amdgcn_mfma_f32_32x32x16_f16(af_l[i], bf_h[j], acc[i][j], 0, 0, 0);
        }
    }
  }

  // epilogue. C/D (32x32, m74/m101): col = lane&31, row = (r&3)+8*(r>>2)+4*half
  float bb[2];
  int gc[2];
#pragma unroll
  for (int j = 0; j < 2; ++j) {
    gc[j] = n0 + wc * 64 + j * 32 + l31;
    bb[j] = bias[gc[j]];
  }
  if constexpr (MODE == 0) {
#pragma unroll
    for (int i = 0; i < 2; ++i)
#pragma unroll
      for (int r = 0; r < 16; ++r) {
        const int row = m0 + wr * 64 + i * 32 + (r & 3) + 8 * (r >> 2) + 4 * half;
#pragma unroll
        for (int j = 0; j < 2; ++j)
          outF[(size_t)row * NTOT + gc[j]] = acc[i][j][r] * INVS + bb[j];
      }
  } else if constexpr (MODE == 1) {
#pragma unroll
    for (int i = 0; i < 2; ++i)
#pragma unroll
      for (int r = 0; r < 16; ++r) {
        const int row = m0 + wr * 64 + i * 32 + (r & 3) + 8 * (r >> 2) + 4 * half;
#pragma unroll
        for (int j = 0; j < 2; ++j) {
          float v = fmaxf(acc[i][j][r] * INVS + bb[j], 0.f) * SCA;
          _Float16 hh, ll;
          fsplit(v, hh, ll);
          outHh[(size_t)row * NTOT + gc[j]] = hh;
          outHl[(size_t)row * NTOT + gc[j]] = ll;
        }
      }
  } else {
    const int slot = blockIdx.y * 2 + wc;   // 32 col-slots of 64
#pragma unroll
    for (int i = 0; i < 2; ++i)
#pragma unroll
      for (int r = 0; r < 16; ++r) {
        float v0 = acc[i][0][r] * INVS + bb[0];
        float v1 = acc[i][1][r] * INVS + bb[1];
        float M;
        int I;
        if (v0 >= v1) { M = v0; I = gc[0]; }          // gc[0]<gc[1]: tie -> first
        else          { M = v1; I = gc[1]; }
        // reduce (M, I) across the 32 cols held by this half-wave
#pragma unroll
        for (int sh = 1; sh <= 16; sh <<= 1) {
          float M2 = __shfl_xor(M, sh);
          int   I2 = __shfl_xor(I, sh);
          if (M2 > M || (M2 == M && I2 < I)) { M = M2; I = I2; }
        }
        float S = __expf(v0 - M) + __expf(v1 - M);
#pragma unroll
        for (int sh = 1; sh <= 16; sh <<= 1) S += __shfl_xor(S, sh);
        if (l31 == 0) {
          const int grow = row0 + m0 + wr * 64 + i * 32 + (r & 3) + 8 * (r >> 2) + 4 * half;
          pM[(size_t)slot * MTOT + grow] = M;
          pS[(size_t)slot * MTOT + grow] = S;
          pI[(size_t)slot * MTOT + grow] = (float)I;
        }
      }
  }
}

// ------- ln_dual: one pass over A+X -> both step activations, split --------
__global__ __launch_bounds__(256) void ln_dual(
    const float* __restrict__ A, const float* __restrict__ X,
    const float* __restrict__ na,
    _Float16* __restrict__ y0h, _Float16* __restrict__ y0l,
    _Float16* __restrict__ y1h, _Float16* __restrict__ y1l, int row0) {
  int t = threadIdx.x;
  int lane = t & 63;
  int w = t >> 6;
  int r = blockIdx.x * 4 + w;          // chunk-local row, one wave per row
  const float* ap = A + (size_t)r * DD + lane * 8;
  const float* xp = X + (size_t)(row0 + r) * DD + lane * 8;
  const float* np = na + lane * 8;
  float v0[8], v1[8];
  float s0 = 0.f, q0 = 0.f, s1 = 0.f, q1 = 0.f;
#pragma unroll
  for (int i = 0; i < 8; ++i) {
    float a = ap[i];
    v0[i] = a + np[i];
    v1[i] = a + xp[i];
    s0 += v0[i]; q0 += v0[i] * v0[i];
    s1 += v1[i]; q1 += v1[i] * v1[i];
  }
#pragma unroll
  for (int m = 1; m <= 32; m <<= 1) {
    s0 += __shfl_xor(s0, m); q0 += __shfl_xor(q0, m);
    s1 += __shfl_xor(s1, m); q1 += __shfl_xor(q1, m);
  }
  float mu0 = s0 * (1.f / DD), mu1 = s1 * (1.f / DD);
  float rs0 = 1.f / sqrtf(q0 * (1.f / DD) - mu0 * mu0 + 1e-5f);
  float rs1 = 1.f / sqrtf(q1 * (1.f / DD) - mu1 * mu1 + 1e-5f);
  _Float16 h0[8], l0[8], h1[8], l1[8];
#pragma unroll
  for (int i = 0; i < 8; ++i) {
    fsplit((v0[i] - mu0) * rs0 * SCA, h0[i], l0[i]);
    fsplit((v1[i] - mu1) * rs1 * SCA, h1[i], l1[i]);
  }
  *(h8*)(y0h + (size_t)r * DD + lane * 8) = *(h8*)h0;
  *(h8*)(y0l + (size_t)r * DD + lane * 8) = *(h8*)l0;
  *(h8*)(y1h + (size_t)r * DD + lane * 8) = *(h8*)h1;
  *(h8*)(y1l + (size_t)r * DD + lane * 8) = *(h8*)l1;
}

// ---------------- finalize: merge 32 partial slots per step ----------------
__global__ void finalize_k(const float* __restrict__ pM0, const float* __restrict__ pS0,
                           const float* __restrict__ pI0, const float* __restrict__ pM1,
                           const float* __restrict__ pS1, const float* __restrict__ pI1,
                           float* __restrict__ out) {
  int r = blockIdx.x * 256 + threadIdx.x;
  float M = pM0[r], S = pS0[r];
  int I = (int)pI0[r];
  for (int s = 1; s < 32; ++s) {
    size_t o = (size_t)s * MTOT + r;
    omerge(M, S, I, pM0[o], pS0[o], (int)pI0[o]);
  }
  float m0v = 1.f / S;
  int i0v = I;
  M = pM1[r]; S = pS1[r]; I = (int)pI1[r];
  for (int s = 1; s < 32; ++s) {
    size_t o = (size_t)s * MTOT + r;
    omerge(M, S, I, pM1[o], pS1[o], (int)pI1[o]);
  }
  float m1v = 1.f / S;
  int i1v = I;
  bool c0 = (i0v != 0) && (m0v >= 0.1f);
  bool c1 = c0 && (i1v != 0) && (m1v >= 0.1f);
  out[r] = c0 ? (c1 ? m0v * m1v : m0v) : 0.f;
  out[MTOT + r] = (float)i0v;
  out[2 * MTOT + r] = (float)i1v;
  out[3 * MTOT + r] = (float)((c0 ? 1 : 0) + (c1 ? 1 : 0));
}

// ---------------- host ----------------
extern "C" void kernel_launch(void* const* d_in, const int* in_sizes, int n_in,
                              void* d_out, int out_size, void* d_ws, size_t ws_size,
                              hipStream_t stream) {
  const float* X   = (const float*)d_in[0];
  const float* na  = (const float*)d_in[1];
  const float* vw  = (const float*)d_in[2];
  const float* vb  = (const float*)d_in[3];
  const float* ow  = (const float*)d_in[4];
  const float* ob  = (const float*)d_in[5];
  const float* lng = (const float*)d_in[6];
  const float* lnb = (const float*)d_in[7];
  const float* w1  = (const float*)d_in[8];
  const float* b1  = (const float*)d_in[9];
  const float* w2  = (const float*)d_in[10];
  const float* b2  = (const float*)d_in[11];
  float* out = (float*)d_out;

  char* p = (char*)d_ws;
  auto alloc = [&](size_t bytes) -> void* {
    void* r = (void*)p;
    p += (bytes + 255) & ~(size_t)255;
    return r;
  };
  _Float16* wvo_h = (_Float16*)alloc(512 * 512 * 2);
  _Float16* wvo_l = (_Float16*)alloc(512 * 512 * 2);
  float*    cvec  = (float*)alloc(512 * 4);
  _Float16* w1p_h = (_Float16*)alloc(1024 * 512 * 2);
  _Float16* w1p_l = (_Float16*)alloc(1024 * 512 * 2);
  float*    b1p   = (float*)alloc(1024 * 4);
  _Float16* w2_h  = (_Float16*)alloc(2048 * 1024 * 2);
  _Float16* w2_l  = (_Float16*)alloc(2048 * 1024 * 2);
  float* pM0 = (float*)alloc((size_t)32 * MTOT * 4);
  float* pS0 = (float*)alloc((size_t)32 * MTOT * 4);
  float* pI0 = (float*)alloc((size_t)32 * MTOT * 4);
  float* pM1 = (float*)alloc((size_t)32 * MTOT * 4);
  float* pS1 = (float*)alloc((size_t)32 * MTOT * 4);
  float* pI1 = (float*)alloc((size_t)32 * MTOT * 4);
  size_t fixed = (size_t)(p - (char*)d_ws);
  size_t remain = ws_size > fixed + 8192 ? ws_size - fixed - 8192 : 0;
  // per-row bytes: Xsplit 2048 + A 2048 + y0split 2048 + Hsplit 4096 = 10240
  // (y1 split aliases the xs buffers -- xs is dead after gemm1)
  int chunk = (int)(remain / 10240);
  chunk &= ~127;
  if (chunk < 128) chunk = 128;
  if (chunk > MTOT) chunk = MTOT;
  _Float16* xs_h = (_Float16*)alloc((size_t)chunk * 512 * 2);
  _Float16* xs_l = (_Float16*)alloc((size_t)chunk * 512 * 2);
  float*    Abuf = (float*)alloc((size_t)chunk * 512 * 4);
  _Float16* y0_h = (_Float16*)alloc((size_t)chunk * 512 * 2);
  _Float16* y0_l = (_Float16*)alloc((size_t)chunk * 512 * 2);
  _Float16* H_h  = (_Float16*)alloc((size_t)chunk * 1024 * 2);
  _Float16* H_l  = (_Float16*)alloc((size_t)chunk * 1024 * 2);
  _Float16* y1_h = xs_h;   // alias: xs consumed by gemm1 before ln_dual writes
  _Float16* y1_l = xs_l;

  prep_wvo_split<<<1024, 256, 0, stream>>>(vw, ow, wvo_h, wvo_l);
  prep_cvec<<<2, 256, 0, stream>>>(ow, vb, ob, cvec);
  prep_w1p_split<<<2048, 256, 0, stream>>>(w1, lng, w1p_h, w1p_l);
  prep_b1p<<<4, 256, 0, stream>>>(w1, lnb, b1, b1p);
  prep_w2_split<<<8192, 256, 0, stream>>>(w2, w2_h, w2_l);

  for (int row0 = 0; row0 < MTOT; row0 += chunk) {
    int rows = (MTOT - row0 < chunk) ? (MTOT - row0) : chunk;
    split_x<<<rows / 4, 256, 0, stream>>>(X + (size_t)row0 * 512, xs_h, xs_l);
    gemm_split<0, 512, 512><<<dim3(rows / 128, 4), 256, 0, stream>>>(
        xs_h, xs_l, wvo_h, wvo_l, cvec, Abuf, nullptr, nullptr,
        nullptr, nullptr, nullptr, 0);
    ln_dual<<<rows / 4, 256, 0, stream>>>(Abuf, X, na, y0_h, y0_l, y1_h, y1_l, row0);
    for (int s = 0; s < 2; ++s) {
      gemm_split<1, 512, 1024><<<dim3(rows / 128, 8), 256, 0, stream>>>(
          s == 0 ? y0_h : y1_h, s == 0 ? y0_l : y1_l, w1p_h, w1p_l, b1p,
          nullptr, H_h, H_l, nullptr, nullptr, nullptr, 0);
      gemm_split<2, 1024, 2048><<<dim3(rows / 128, 16), 256, 0, stream>>>(
          H_h, H_l, w2_h, w2_l, b2, nullptr, nullptr, nullptr,
          s == 0 ? pM0 : pM1, s == 0 ? pS0 : pS1, s == 0 ? pI0 : pI1, row0);
    }
  }
  finalize_k<<<MTOT / 256, 256, 0, stream>>>(pM0, pS0, pI0, pM1, pS1, pI1, out);
}

// Round 5
// 1634.637 us; speedup vs baseline: 3.6866x; 1.0279x over previous
//
#include <hip/hip_runtime.h>
#include <math.h>

#define MTOT 32768   // B*R
#define DD   512
#define HHD  1024
#define NRELN 2048
#define SCA  64.f          // activation fp16 pre-scale
#define SCB  1024.f        // weight fp16 pre-scale
#define INVS (1.f / 65536.f)
#define CAPR 4096          // rescue row capacity (expected ~1300/step)
#define MARGIN 2.0e-3f     // approx-gap rescue threshold (~50 sigma of approx err)

typedef _Float16 h8  __attribute__((ext_vector_type(8)));
typedef float    f16v __attribute__((ext_vector_type(16)));

__device__ __forceinline__ void fsplit(float x, _Float16& h, _Float16& l) {
  _Float16 t = (_Float16)x;
  h = t;
  l = (_Float16)(x - (float)t);   // hi/lo split: 2^-22 rel error total
}

__device__ __forceinline__ void gld16(const _Float16* g, _Float16* l) {
  __builtin_amdgcn_global_load_lds(
      (const __attribute__((address_space(1))) void*)g,
      (__attribute__((address_space(3))) void*)l, 16, 0, 0);
}

// ---------------- prep: fold + scale + split weights ----------------

__global__ void prep_wvo_split(const float* __restrict__ vw, const float* __restrict__ ow,
                               _Float16* __restrict__ wh, _Float16* __restrict__ wl) {
  int idx = blockIdx.x * 256 + threadIdx.x;   // 512*512
  int k = idx & 511;
  int n = idx >> 9;
  float s = 0.f;
  for (int j = 0; j < DD; ++j) s += ow[n * DD + j] * vw[j * DD + k];
  fsplit(s * SCB, wh[n * DD + k], wl[n * DD + k]);
}

__global__ void prep_cvec(const float* __restrict__ ow, const float* __restrict__ vb,
                          const float* __restrict__ ob, float* __restrict__ c) {
  int i = blockIdx.x * 256 + threadIdx.x;
  if (i < DD) {
    float s = ob[i];
    for (int k = 0; k < DD; ++k) s += ow[i * DD + k] * vb[k];
    c[i] = s;
  }
}

__global__ void prep_w1p_split(const float* __restrict__ w1, const float* __restrict__ g,
                               _Float16* __restrict__ wh, _Float16* __restrict__ wl) {
  int idx = blockIdx.x * 256 + threadIdx.x;   // 1024*512
  int k = idx & 511;
  int n = idx >> 9;
  fsplit(w1[n * DD + k] * g[k] * SCB, wh[n * DD + k], wl[n * DD + k]);
}

__global__ void prep_b1p(const float* __restrict__ w1, const float* __restrict__ lnb,
                         const float* __restrict__ b1, float* __restrict__ b1p) {
  int n = blockIdx.x * 256 + threadIdx.x;
  if (n < HHD) {
    float s = b1[n];
    for (int k = 0; k < DD; ++k) s += w1[n * DD + k] * lnb[k];
    b1p[n] = s;
  }
}

__global__ void prep_w2_split(const float* __restrict__ w2,
                              _Float16* __restrict__ wh, _Float16* __restrict__ wl) {
  int idx = blockIdx.x * 256 + threadIdx.x;   // 2048*1024
  int k = idx & 1023;
  int n = idx >> 10;
  fsplit(w2[n * HHD + k] * SCB, wh[n * HHD + k], wl[n * HHD + k]);
}

__global__ void split_x(const float* __restrict__ src, _Float16* __restrict__ h,
                        _Float16* __restrict__ l) {
  int idx = (blockIdx.x * 256 + threadIdx.x) * 8;
  float4 a = *(const float4*)(src + idx);
  float4 b = *(const float4*)(src + idx + 4);
  float vv[8] = {a.x, a.y, a.z, a.w, b.x, b.y, b.z, b.w};
  _Float16 hh[8], ll[8];
#pragma unroll
  for (int i = 0; i < 8; ++i) fsplit(vv[i] * SCA, hh[i], ll[i]);
  *(h8*)(h + idx) = *(h8*)hh;
  *(h8*)(l + idx) = *(h8*)ll;
}

__global__ void zero_cnt(int* c) { c[blockIdx.x * 256 + threadIdx.x] = 0; }

// ---------------- exact fp16-split GEMM (3-product), 128x128, BK=32 ----------
// SW(r) = ((r>>1)^(r>>3))&3 chunk swizzle.
// MODE 0: +bias -> fp32 out. MODE 1: +bias, relu, *SCA, split -> H.
// MODE 2: rescue rows (count from *cntp, grid-stride): per-row (max, argmax)
//         -> pM/pI partials (32 col-slots), stride pstr.
template <int MODE, int KDIM, int NTOT>
__global__ __launch_bounds__(256) void gemm_split(
    const _Float16* __restrict__ Ah, const _Float16* __restrict__ Al,
    const _Float16* __restrict__ Bh, const _Float16* __restrict__ Bl,
    const float* __restrict__ bias,
    float* __restrict__ outF,
    _Float16* __restrict__ outHh, _Float16* __restrict__ outHl,
    float* __restrict__ pM, float* __restrict__ pI,
    const int* __restrict__ cntp, int pstr) {
  __shared__ __align__(16) _Float16 sA[2][128][32];
  __shared__ __align__(16) _Float16 sB[2][128][32];
  const int t = threadIdx.x;
  const int lane = t & 63;
  const int wv = t >> 6;
  const int wr = wv & 1, wc = wv >> 1;
  const int l31 = lane & 31, half = lane >> 5;
  const int n0 = blockIdx.y << 7;

  const _Float16* gsp = (wv == 0) ? Ah : (wv == 1) ? Al : (wv == 2) ? Bh : Bl;
  _Float16* lbase = (wv == 0) ? &sA[0][0][0] : (wv == 1) ? &sA[1][0][0]
                  : (wv == 2) ? &sB[0][0][0] : &sB[1][0][0];
  const int srow = lane >> 2;
  const int scp = lane & 3;
  const int swzE = ((srow >> 1) & 3) ^ ((srow >> 3) & 1);
  const int swzO = swzE ^ 2;
  const int swz = ((l31 >> 1) ^ (l31 >> 3)) & 3;   // frag-read side

  int nmb;
  if constexpr (MODE == 2) {
    int a = *cntp;
    if (a > CAPR) a = CAPR;
    nmb = (a + 127) >> 7;
  } else {
    nmb = gridDim.x;
  }

  for (int mb = blockIdx.x; mb < nmb; mb += gridDim.x) {
    const int m0 = mb << 7;
    const int gb = (wv < 2) ? m0 : n0;
    const _Float16* gA0 = gsp + (size_t)(gb + srow) * KDIM + ((scp ^ swzE) << 3);
    const _Float16* gA1 = gsp + (size_t)(gb + srow) * KDIM + ((scp ^ swzO) << 3);

    f16v acc[2][2] = {};
    for (int k0 = 0; k0 < KDIM; k0 += 32) {
      __syncthreads();
#pragma unroll
      for (int it = 0; it < 8; ++it)
        gld16(((it & 1) ? gA1 : gA0) + (size_t)(it * 16) * KDIM + k0, lbase + it * 512);
      __syncthreads();
#pragma unroll
      for (int ks = 0; ks < 2; ++ks) {
        const int pos = (((ks << 1) + half) ^ swz) << 3;
        h8 af_h[2], af_l[2], bf_h[2], bf_l[2];
#pragma unroll
        for (int i = 0; i < 2; ++i) {
          const int mr = wr * 64 + i * 32 + l31;
          af_h[i] = *(const h8*)&sA[0][mr][pos];
          af_l[i] = *(const h8*)&sA[1][mr][pos];
        }
#pragma unroll
        for (int j = 0; j < 2; ++j) {
          const int nr = wc * 64 + j * 32 + l31;
          bf_h[j] = *(const h8*)&sB[0][nr][pos];
          bf_l[j] = *(const h8*)&sB[1][nr][pos];
        }
#pragma unroll
        for (int j = 0; j < 2; ++j)
#pragma unroll
          for (int i = 0; i < 2; ++i) {
            acc[i][j] = __builtin_amdgcn_mfma_f32_32x32x16_f16(af_h[i], bf_h[j], acc[i][j], 0, 0, 0);
            acc[i][j] = __builtin_amdgcn_mfma_f32_32x32x16_f16(af_h[i], bf_l[j], acc[i][j], 0, 0, 0);
            acc[i][j] = __builtin_amdgcn_mfma_f32_32x32x16_f16(af_l[i], bf_h[j], acc[i][j], 0, 0, 0);
          }
      }
    }

    // C/D (32x32): col = lane&31, row = (r&3)+8*(r>>2)+4*half
    float bb[2];
    int gc[2];
#pragma unroll
    for (int j = 0; j < 2; ++j) {
      gc[j] = n0 + wc * 64 + j * 32 + l31;
      bb[j] = bias[gc[j]];
    }
    if constexpr (MODE == 0) {
#pragma unroll
      for (int i = 0; i < 2; ++i)
#pragma unroll
        for (int r = 0; r < 16; ++r) {
          const int row = m0 + wr * 64 + i * 32 + (r & 3) + 8 * (r >> 2) + 4 * half;
#pragma unroll
          for (int j = 0; j < 2; ++j)
            outF[(size_t)row * NTOT + gc[j]] = acc[i][j][r] * INVS + bb[j];
        }
    } else if constexpr (MODE == 1) {
#pragma unroll
      for (int i = 0; i < 2; ++i)
#pragma unroll
        for (int r = 0; r < 16; ++r) {
          const int row = m0 + wr * 64 + i * 32 + (r & 3) + 8 * (r >> 2) + 4 * half;
#pragma unroll
          for (int j = 0; j < 2; ++j) {
            float v = fmaxf(acc[i][j][r] * INVS + bb[j], 0.f) * SCA;
            _Float16 hh, ll;
            fsplit(v, hh, ll);
            outHh[(size_t)row * NTOT + gc[j]] = hh;
            outHl[(size_t)row * NTOT + gc[j]] = ll;
          }
        }
    } else {
      const int slot = blockIdx.y * 2 + wc;   // 32 col-slots of 64
#pragma unroll
      for (int i = 0; i < 2; ++i)
#pragma unroll
        for (int r = 0; r < 16; ++r) {
          float v0 = acc[i][0][r] * INVS + bb[0];
          float v1 = acc[i][1][r] * INVS + bb[1];
          float M;
          int I;
          if (v0 >= v1) { M = v0; I = gc[0]; }
          else          { M = v1; I = gc[1]; }
#pragma unroll
          for (int sh = 1; sh <= 16; sh <<= 1) {
            float M2 = __shfl_xor(M, sh);
            int   I2 = __shfl_xor(I, sh);
            if (M2 > M || (M2 == M && I2 < I)) { M = M2; I = I2; }
          }
          if (l31 == 0) {
            const int grow = m0 + wr * 64 + i * 32 + (r & 3) + 8 * (r >> 2) + 4 * half;
            pM[(size_t)slot * pstr + grow] = M;
            pI[(size_t)slot * pstr + grow] = (float)I;
          }
        }
    }
  }
}

// ---------------- approx GEMM (hh only), 128x256 tile, BK=32 ----------------
// A = Hh [rows][1024] (chunk-local), B = w2h [2048][1024]. 4 waves, each
// 64x128 via 2Mx4N frags of 32x32x16. Epilogue: per-row online (max, 2nd-max,
// first-argmax, sumexp) -> 16 col-slots, stride astr (chunk-local rows).
__global__ __launch_bounds__(256) void gemm_approx(
    const _Float16* __restrict__ Ah, const _Float16* __restrict__ Bh,
    const float* __restrict__ bias,
    float* __restrict__ pM, float* __restrict__ pM2,
    float* __restrict__ pS, int* __restrict__ pI, int astr) {
  __shared__ __align__(16) _Float16 sAB[12288];   // A 128x32 | B 256x32
  const int t = threadIdx.x;
  const int lane = t & 63;
  const int wv = t >> 6;
  const int wr = wv & 1, wc = wv >> 1;
  const int l31 = lane & 31, half = lane >> 5;
  const int m0 = blockIdx.x << 7;
  const int n0 = blockIdx.y << 8;

  const _Float16* gsrc[6];
  _Float16* ldst[6];
#pragma unroll
  for (int it = 0; it < 6; ++it) {
    int p = (it * 4 + wv) * 64 + lane;
    const _Float16* s;
    if (p < 512) {
      int row = p >> 2, cp = p & 3;
      int sw = ((row >> 1) ^ (row >> 3)) & 3;
      s = Ah + (size_t)(m0 + row) * HHD + ((cp ^ sw) << 3);
    } else {
      int pq = p - 512;
      int row = pq >> 2, cp = pq & 3;
      int sw = ((row >> 1) ^ (row >> 3)) & 3;
      s = Bh + (size_t)(n0 + row) * HHD + ((cp ^ sw) << 3);
    }
    gsrc[it] = s;
    ldst[it] = sAB + (size_t)(it * 4 + wv) * 512;
  }
  const int swz = ((l31 >> 1) ^ (l31 >> 3)) & 3;

  f16v acc[2][4] = {};
  for (int k0 = 0; k0 < HHD; k0 += 32) {
    __syncthreads();
#pragma unroll
    for (int it = 0; it < 6; ++it) gld16(gsrc[it] + k0, ldst[it]);
    __syncthreads();
#pragma unroll
    for (int ks = 0; ks < 2; ++ks) {
      const int pos = (((ks << 1) + half) ^ swz) << 3;
      h8 af[2], bf[4];
#pragma unroll
      for (int i = 0; i < 2; ++i)
        af[i] = *(const h8*)&sAB[(size_t)(wr * 64 + i * 32 + l31) * 32 + pos];
#pragma unroll
      for (int j = 0; j < 4; ++j)
        bf[j] = *(const h8*)&sAB[4096 + (size_t)(wc * 128 + j * 32 + l31) * 32 + pos];
#pragma unroll
      for (int j = 0; j < 4; ++j)
#pragma unroll
        for (int i = 0; i < 2; ++i)
          acc[i][j] = __builtin_amdgcn_mfma_f32_32x32x16_f16(af[i], bf[j], acc[i][j], 0, 0, 0);
    }
  }

  const int slot = blockIdx.y * 2 + wc;   // 16 slots of 128 cols
  float bb[4];
  int gc[4];
#pragma unroll
  for (int j = 0; j < 4; ++j) {
    gc[j] = n0 + wc * 128 + j * 32 + l31;
    bb[j] = bias[gc[j]];
  }
#pragma unroll
  for (int i = 0; i < 2; ++i)
#pragma unroll
    for (int r = 0; r < 16; ++r) {
      float M = acc[i][0][r] * INVS + bb[0], M2 = -INFINITY, S = 1.f;
      int I = gc[0];
#pragma unroll
      for (int j = 1; j < 4; ++j) {
        float v = acc[i][j][r] * INVS + bb[j];
        if (v > M || (v == M && gc[j] < I)) {
          S = S * __expf(M - v) + 1.f; M2 = M; M = v; I = gc[j];
        } else {
          S += __expf(v - M); M2 = fmaxf(M2, v);
        }
      }
#pragma unroll
      for (int sh = 1; sh <= 16; sh <<= 1) {
        float Mo = __shfl_xor(M, sh);
        float M2o = __shfl_xor(M2, sh);
        float So = __shfl_xor(S, sh);
        int   Io = __shfl_xor(I, sh);
        if (Mo > M || (Mo == M && Io < I)) {
          S = S * __expf(M - Mo) + So; M2 = fmaxf(M, M2o); M = Mo; I = Io;
        } else {
          S += So * __expf(Mo - M); M2 = fmaxf(M2, Mo);
        }
      }
      if (l31 == 0) {
        const int grow = m0 + wr * 64 + i * 32 + (r & 3) + 8 * (r >> 2) + 4 * half;
        pM[(size_t)slot * astr + grow] = M;
        pM2[(size_t)slot * astr + grow] = M2;
        pS[(size_t)slot * astr + grow] = S;
        pI[(size_t)slot * astr + grow] = I;
      }
    }
}

// -------- flag: merge 16 approx slots; emit m/i; flag small gaps ----
__global__ void flag_k(const float* __restrict__ pM, const float* __restrict__ pM2,
                       const float* __restrict__ pS, const int* __restrict__ pI,
                       int astr, int rows,
                       float* __restrict__ map, int* __restrict__ iap, int row0,
                       int* __restrict__ list, int* __restrict__ cnt) {
  int r = blockIdx.x * 256 + threadIdx.x;
  if (r >= rows) return;
  float M = pM[r], M2 = pM2[r], S = pS[r];
  int I = pI[r];
  for (int s = 1; s < 16; ++s) {
    size_t o = (size_t)s * astr + r;
    float m = pM[o], m2 = pM2[o], ss = pS[o];
    int ii = pI[o];
    if (m > M || (m == M && ii < I)) {
      M2 = fmaxf(M, m2); S = S * __expf(M - m) + ss; M = m; I = ii;
    } else {
      M2 = fmaxf(M2, m); S += ss * __expf(m - M);
    }
  }
  map[row0 + r] = 1.f / S;
  iap[row0 + r] = I;
  if (M - M2 < MARGIN) {
    int c = atomicAdd(cnt, 1);
    if (c < CAPR) list[c] = r;   // chunk-local row
  }
}

// -------- gather flagged H rows (exact split) into dense rescue buffer ------
__global__ void gather_k(const _Float16* __restrict__ Hh, const _Float16* __restrict__ Hl,
                         const int* __restrict__ list, const int* __restrict__ cnt,
                         _Float16* __restrict__ Gh, _Float16* __restrict__ Gl) {
  int b = blockIdx.x;
  int active = *cnt;
  if (active > CAPR) active = CAPR;
  if (b >= active) return;
  int r = list[b];
  int t = threadIdx.x;   // 128 threads x 8 halfs = 1024
  *(h8*)(Gh + (size_t)b * HHD + t * 8) = *(const h8*)(Hh + (size_t)r * HHD + t * 8);
  *(h8*)(Gl + (size_t)b * HHD + t * 8) = *(const h8*)(Hl + (size_t)r * HHD + t * 8);
}

// -------- rescue merge: exact argmax over 32 slots -> overwrite iap ---------
__global__ void rescue_merge(const float* __restrict__ pMr, const float* __restrict__ pIr,
                             const int* __restrict__ list, const int* __restrict__ cnt,
                             int* __restrict__ iap, int row0) {
  int c = blockIdx.x * 256 + threadIdx.x;
  int a = *cnt;
  if (a > CAPR) a = CAPR;
  if (c >= a) return;
  float M = pMr[c];
  int I = (int)pIr[c];
  for (int s = 1; s < 32; ++s) {
    size_t o = (size_t)s * CAPR + c;
    float m = pMr[o];
    int i2 = (int)pIr[o];
    if (m > M || (m == M && i2 < I)) { M = m; I = i2; }
  }
  iap[row0 + list[c]] = I;
}

// ------- ln_dual: one pass over A+X -> both step activations, split --------
__global__ __launch_bounds__(256) void ln_dual(
    const float* __restrict__ A, const float* __restrict__ X,
    const float* __restrict__ na,
    _Float16* __restrict__ y0h, _Float16* __restrict__ y0l,
    _Float16* __restrict__ y1h, _Float16* __restrict__ y1l) {
  int t = threadIdx.x;
  int lane = t & 63;
  int w = t >> 6;
  int r = blockIdx.x * 4 + w;
  const float* ap = A + (size_t)r * DD + lane * 8;
  const float* xp = X + (size_t)r * DD + lane * 8;
  const float* np = na + lane * 8;
  float v0[8], v1[8];
  float s0 = 0.f, q0 = 0.f, s1 = 0.f, q1 = 0.f;
#pragma unroll
  for (int i = 0; i < 8; ++i) {
    float a = ap[i];
    v0[i] = a + np[i];
    v1[i] = a + xp[i];
    s0 += v0[i]; q0 += v0[i] * v0[i];
    s1 += v1[i]; q1 += v1[i] * v1[i];
  }
#pragma unroll
  for (int m = 1; m <= 32; m <<= 1) {
    s0 += __shfl_xor(s0, m); q0 += __shfl_xor(q0, m);
    s1 += __shfl_xor(s1, m); q1 += __shfl_xor(q1, m);
  }
  float mu0 = s0 * (1.f / DD), mu1 = s1 * (1.f / DD);
  float rs0 = 1.f / sqrtf(q0 * (1.f / DD) - mu0 * mu0 + 1e-5f);
  float rs1 = 1.f / sqrtf(q1 * (1.f / DD) - mu1 * mu1 + 1e-5f);
  _Float16 h0[8], l0[8], h1[8], l1[8];
#pragma unroll
  for (int i = 0; i < 8; ++i) {
    fsplit((v0[i] - mu0) * rs0 * SCA, h0[i], l0[i]);
    fsplit((v1[i] - mu1) * rs1 * SCA, h1[i], l1[i]);
  }
  *(h8*)(y0h + (size_t)r * DD + lane * 8) = *(h8*)h0;
  *(h8*)(y0l + (size_t)r * DD + lane * 8) = *(h8*)l0;
  *(h8*)(y1h + (size_t)r * DD + lane * 8) = *(h8*)h1;
  *(h8*)(y1l + (size_t)r * DD + lane * 8) = *(h8*)l1;
}

// ---------------- finalize ----------------
__global__ void finalize_k(const float* __restrict__ map0, const int* __restrict__ iap0,
                           const float* __restrict__ map1, const int* __restrict__ iap1,
                           float* __restrict__ out) {
  int r = blockIdx.x * 256 + threadIdx.x;
  float m0v = map0[r], m1v = map1[r];
  int i0v = iap0[r], i1v = iap1[r];
  bool c0 = (i0v != 0) && (m0v >= 0.1f);
  bool c1 = c0 && (i1v != 0) && (m1v >= 0.1f);
  out[r] = c0 ? (c1 ? m0v * m1v : m0v) : 0.f;
  out[MTOT + r] = (float)i0v;
  out[2 * MTOT + r] = (float)i1v;
  out[3 * MTOT + r] = (float)((c0 ? 1 : 0) + (c1 ? 1 : 0));
}

// ---------------- host ----------------
extern "C" void kernel_launch(void* const* d_in, const int* in_sizes, int n_in,
                              void* d_out, int out_size, void* d_ws, size_t ws_size,
                              hipStream_t stream) {
  const float* X   = (const float*)d_in[0];
  const float* na  = (const float*)d_in[1];
  const float* vw  = (const float*)d_in[2];
  const float* vb  = (const float*)d_in[3];
  const float* ow  = (const float*)d_in[4];
  const float* ob  = (const float*)d_in[5];
  const float* lng = (const float*)d_in[6];
  const float* lnb = (const float*)d_in[7];
  const float* w1  = (const float*)d_in[8];
  const float* b1  = (const float*)d_in[9];
  const float* w2  = (const float*)d_in[10];
  const float* b2  = (const float*)d_in[11];
  float* out = (float*)d_out;

  char* p = (char*)d_ws;
  auto alloc = [&](size_t bytes) -> void* {
    void* r = (void*)p;
    p += (bytes + 255) & ~(size_t)255;
    return r;
  };
  // ---- fixed allocations (~30 MB) ----
  _Float16* wvo_h = (_Float16*)alloc(512 * 512 * 2);
  _Float16* wvo_l = (_Float16*)alloc(512 * 512 * 2);
  float*    cvec  = (float*)alloc(512 * 4);
  _Float16* w1p_h = (_Float16*)alloc(1024 * 512 * 2);
  _Float16* w1p_l = (_Float16*)alloc(1024 * 512 * 2);
  float*    b1p   = (float*)alloc(1024 * 4);
  _Float16* w2_h  = (_Float16*)alloc(2048 * 1024 * 2);
  _Float16* w2_l  = (_Float16*)alloc(2048 * 1024 * 2);
  float* map0 = (float*)alloc((size_t)MTOT * 4);
  float* map1 = (float*)alloc((size_t)MTOT * 4);
  int* iap0 = (int*)alloc((size_t)MTOT * 4);
  int* iap1 = (int*)alloc((size_t)MTOT * 4);
  int* list = (int*)alloc(CAPR * 4);
  int* cnt  = (int*)alloc(512 * 4);   // per-(chunk,step) counters
  float* pMr = (float*)alloc((size_t)32 * CAPR * 4);
  float* pIr = (float*)alloc((size_t)32 * CAPR * 4);
  _Float16* Gh = (_Float16*)alloc((size_t)CAPR * HHD * 2);
  _Float16* Gl = (_Float16*)alloc((size_t)CAPR * HHD * 2);

  // ---- chunk sizing: per-row bytes = xs 2048 + A 2048 + y0 2048 + H 4096
  //      + approx partials 256 = 10496 ----
  size_t fixed = (size_t)(p - (char*)d_ws);
  size_t reserve = 2u << 20;
  size_t remain = ws_size > fixed + reserve ? ws_size - fixed - reserve : 0;
  int chunk = (int)(remain / 10496);
  chunk &= ~127;
  if (chunk < 128) chunk = 128;
  if (chunk > MTOT) chunk = MTOT;

  _Float16* xs_h = (_Float16*)alloc((size_t)chunk * 512 * 2);
  _Float16* xs_l = (_Float16*)alloc((size_t)chunk * 512 * 2);
  float*    Abuf = (float*)alloc((size_t)chunk * 512 * 4);
  _Float16* y0_h = (_Float16*)alloc((size_t)chunk * 512 * 2);
  _Float16* y0_l = (_Float16*)alloc((size_t)chunk * 512 * 2);
  _Float16* H_h  = (_Float16*)alloc((size_t)chunk * 1024 * 2);
  _Float16* H_l  = (_Float16*)alloc((size_t)chunk * 1024 * 2);
  float* pMa  = (float*)alloc((size_t)16 * chunk * 4);
  float* pM2a = (float*)alloc((size_t)16 * chunk * 4);
  float* pSa  = (float*)alloc((size_t)16 * chunk * 4);
  int*   pIa  = (int*)alloc((size_t)16 * chunk * 4);
  _Float16* y1_h = xs_h;   // alias: xs consumed by gemm1 before ln_dual writes
  _Float16* y1_l = xs_l;

  zero_cnt<<<2, 256, 0, stream>>>(cnt);
  prep_wvo_split<<<1024, 256, 0, stream>>>(vw, ow, wvo_h, wvo_l);
  prep_cvec<<<2, 256, 0, stream>>>(ow, vb, ob, cvec);
  prep_w1p_split<<<2048, 256, 0, stream>>>(w1, lng, w1p_h, w1p_l);
  prep_b1p<<<4, 256, 0, stream>>>(w1, lnb, b1, b1p);
  prep_w2_split<<<8192, 256, 0, stream>>>(w2, w2_h, w2_l);

  int citer = 0;
  for (int row0 = 0; row0 < MTOT; row0 += chunk, ++citer) {
    int rows = (MTOT - row0 < chunk) ? (MTOT - row0) : chunk;
    split_x<<<rows * 512 / 2048, 256, 0, stream>>>(X + (size_t)row0 * 512, xs_h, xs_l);
    gemm_split<0, 512, 512><<<dim3(rows / 128, 4), 256, 0, stream>>>(
        xs_h, xs_l, wvo_h, wvo_l, cvec, Abuf, nullptr, nullptr,
        nullptr, nullptr, nullptr, 0);
    ln_dual<<<rows / 4, 256, 0, stream>>>(Abuf, X + (size_t)row0 * 512, na,
                                          y0_h, y0_l, y1_h, y1_l);
    for (int s = 0; s < 2; ++s) {
      int* cp = cnt + citer * 2 + s;
      gemm_split<1, 512, 1024><<<dim3(rows / 128, 8), 256, 0, stream>>>(
          s == 0 ? y0_h : y1_h, s == 0 ? y0_l : y1_l, w1p_h, w1p_l, b1p,
          nullptr, H_h, H_l, nullptr, nullptr, nullptr, 0);
      gemm_approx<<<dim3(rows / 128, 8), 256, 0, stream>>>(
          H_h, w2_h, b2, pMa, pM2a, pSa, pIa, chunk);
      flag_k<<<(rows + 255) / 256, 256, 0, stream>>>(
          pMa, pM2a, pSa, pIa, chunk, rows,
          s == 0 ? map0 : map1, s == 0 ? iap0 : iap1, row0, list, cp);
      gather_k<<<CAPR, 128, 0, stream>>>(H_h, H_l, list, cp, Gh, Gl);
      gemm_split<2, 1024, 2048><<<dim3(8, 16), 256, 0, stream>>>(
          Gh, Gl, w2_h, w2_l, b2, nullptr, nullptr, nullptr,
          pMr, pIr, cp, CAPR);
      rescue_merge<<<CAPR / 256, 256, 0, stream>>>(
          pMr, pIr, list, cp, s == 0 ? iap0 : iap1, row0);
    }
  }
  finalize_k<<<MTOT / 256, 256, 0, stream>>>(map0, iap0, map1, iap1, out);
}

// Round 6
// 1591.128 us; speedup vs baseline: 3.7874x; 1.0273x over previous
//
#include <hip/hip_runtime.h>
#include <math.h>

#define MTOT 32768   // B*R
#define DD   512
#define HHD  1024
#define NRELN 2048
#define SCA  64.f          // activation fp16 pre-scale
#define SCB  1024.f        // weight fp16 pre-scale
#define INVS (1.f / 65536.f)
#define CAPR 4096          // rescue row capacity (expected ~1300/step)
#define MARGIN 2.0e-3f     // approx-gap rescue threshold (~50 sigma of approx err)

typedef _Float16 h8  __attribute__((ext_vector_type(8)));
typedef float    f4  __attribute__((ext_vector_type(4)));
typedef float    f16v __attribute__((ext_vector_type(16)));

__device__ __forceinline__ void fsplit(float x, _Float16& h, _Float16& l) {
  _Float16 t = (_Float16)x;
  h = t;
  l = (_Float16)(x - (float)t);   // hi/lo split: 2^-22 rel error total
}

__device__ __forceinline__ void gld16(const _Float16* g, _Float16* l) {
  __builtin_amdgcn_global_load_lds(
      (const __attribute__((address_space(1))) void*)g,
      (__attribute__((address_space(3))) void*)l, 16, 0, 0);
}

// ---------------- prep: fold + scale + split weights ----------------

__global__ void prep_wvo_split(const float* __restrict__ vw, const float* __restrict__ ow,
                               _Float16* __restrict__ wh, _Float16* __restrict__ wl) {
  int idx = blockIdx.x * 256 + threadIdx.x;   // 512*512
  int k = idx & 511;
  int n = idx >> 9;
  float s = 0.f;
  for (int j = 0; j < DD; ++j) s += ow[n * DD + j] * vw[j * DD + k];
  fsplit(s * SCB, wh[n * DD + k], wl[n * DD + k]);
}

__global__ void prep_cvec(const float* __restrict__ ow, const float* __restrict__ vb,
                          const float* __restrict__ ob, float* __restrict__ c) {
  int i = blockIdx.x * 256 + threadIdx.x;
  if (i < DD) {
    float s = ob[i];
    for (int k = 0; k < DD; ++k) s += ow[i * DD + k] * vb[k];
    c[i] = s;
  }
}

__global__ void prep_w1p_split(const float* __restrict__ w1, const float* __restrict__ g,
                               _Float16* __restrict__ wh, _Float16* __restrict__ wl) {
  int idx = blockIdx.x * 256 + threadIdx.x;   // 1024*512
  int k = idx & 511;
  int n = idx >> 9;
  fsplit(w1[n * DD + k] * g[k] * SCB, wh[n * DD + k], wl[n * DD + k]);
}

__global__ void prep_b1p(const float* __restrict__ w1, const float* __restrict__ lnb,
                         const float* __restrict__ b1, float* __restrict__ b1p) {
  int n = blockIdx.x * 256 + threadIdx.x;
  if (n < HHD) {
    float s = b1[n];
    for (int k = 0; k < DD; ++k) s += w1[n * DD + k] * lnb[k];
    b1p[n] = s;
  }
}

__global__ void prep_w2_split(const float* __restrict__ w2,
                              _Float16* __restrict__ wh, _Float16* __restrict__ wl) {
  int idx = blockIdx.x * 256 + threadIdx.x;   // 2048*1024
  int k = idx & 1023;
  int n = idx >> 10;
  fsplit(w2[n * HHD + k] * SCB, wh[n * HHD + k], wl[n * HHD + k]);
}

__global__ void split_x(const float* __restrict__ src, _Float16* __restrict__ h,
                        _Float16* __restrict__ l) {
  int idx = (blockIdx.x * 256 + threadIdx.x) * 8;
  float4 a = *(const float4*)(src + idx);
  float4 b = *(const float4*)(src + idx + 4);
  float vv[8] = {a.x, a.y, a.z, a.w, b.x, b.y, b.z, b.w};
  _Float16 hh[8], ll[8];
#pragma unroll
  for (int i = 0; i < 8; ++i) fsplit(vv[i] * SCA, hh[i], ll[i]);
  *(h8*)(h + idx) = *(h8*)hh;
  *(h8*)(l + idx) = *(h8*)ll;
}

__global__ void zero_cnt(int* c) { c[blockIdx.x * 256 + threadIdx.x] = 0; }

// ---------------- exact fp16-split GEMM (3-product), 128x128, BK=32 ----------
// SW(r) = ((r>>1)^(r>>3))&3 chunk swizzle.
// MODE 0: +bias -> fp32 out. MODE 1: +bias, relu, *SCA, split -> H.
// MODE 2: rescue rows (count from *cntp, grid-stride): per-row (max, argmax)
//         -> pM/pI partials (32 col-slots), stride pstr.
template <int MODE, int KDIM, int NTOT>
__global__ __launch_bounds__(256) void gemm_split(
    const _Float16* __restrict__ Ah, const _Float16* __restrict__ Al,
    const _Float16* __restrict__ Bh, const _Float16* __restrict__ Bl,
    const float* __restrict__ bias,
    float* __restrict__ outF,
    _Float16* __restrict__ outHh, _Float16* __restrict__ outHl,
    float* __restrict__ pM, float* __restrict__ pI,
    const int* __restrict__ cntp, int pstr) {
  __shared__ __align__(16) _Float16 sA[2][128][32];
  __shared__ __align__(16) _Float16 sB[2][128][32];
  const int t = threadIdx.x;
  const int lane = t & 63;
  const int wv = t >> 6;
  const int wr = wv & 1, wc = wv >> 1;
  const int l31 = lane & 31, half = lane >> 5;
  const int n0 = blockIdx.y << 7;

  const _Float16* gsp = (wv == 0) ? Ah : (wv == 1) ? Al : (wv == 2) ? Bh : Bl;
  _Float16* lbase = (wv == 0) ? &sA[0][0][0] : (wv == 1) ? &sA[1][0][0]
                  : (wv == 2) ? &sB[0][0][0] : &sB[1][0][0];
  const int srow = lane >> 2;
  const int scp = lane & 3;
  const int swzE = ((srow >> 1) & 3) ^ ((srow >> 3) & 1);
  const int swzO = swzE ^ 2;
  const int swz = ((l31 >> 1) ^ (l31 >> 3)) & 3;   // frag-read side

  int nmb;
  if constexpr (MODE == 2) {
    int a = *cntp;
    if (a > CAPR) a = CAPR;
    nmb = (a + 127) >> 7;
  } else {
    nmb = gridDim.x;
  }

  for (int mb = blockIdx.x; mb < nmb; mb += gridDim.x) {
    const int m0 = mb << 7;
    const int gb = (wv < 2) ? m0 : n0;
    const _Float16* gA0 = gsp + (size_t)(gb + srow) * KDIM + ((scp ^ swzE) << 3);
    const _Float16* gA1 = gsp + (size_t)(gb + srow) * KDIM + ((scp ^ swzO) << 3);

    f16v acc[2][2] = {};
    for (int k0 = 0; k0 < KDIM; k0 += 32) {
      __syncthreads();
#pragma unroll
      for (int it = 0; it < 8; ++it)
        gld16(((it & 1) ? gA1 : gA0) + (size_t)(it * 16) * KDIM + k0, lbase + it * 512);
      __syncthreads();
#pragma unroll
      for (int ks = 0; ks < 2; ++ks) {
        const int pos = (((ks << 1) + half) ^ swz) << 3;
        h8 af_h[2], af_l[2], bf_h[2], bf_l[2];
#pragma unroll
        for (int i = 0; i < 2; ++i) {
          const int mr = wr * 64 + i * 32 + l31;
          af_h[i] = *(const h8*)&sA[0][mr][pos];
          af_l[i] = *(const h8*)&sA[1][mr][pos];
        }
#pragma unroll
        for (int j = 0; j < 2; ++j) {
          const int nr = wc * 64 + j * 32 + l31;
          bf_h[j] = *(const h8*)&sB[0][nr][pos];
          bf_l[j] = *(const h8*)&sB[1][nr][pos];
        }
#pragma unroll
        for (int j = 0; j < 2; ++j)
#pragma unroll
          for (int i = 0; i < 2; ++i) {
            acc[i][j] = __builtin_amdgcn_mfma_f32_32x32x16_f16(af_h[i], bf_h[j], acc[i][j], 0, 0, 0);
            acc[i][j] = __builtin_amdgcn_mfma_f32_32x32x16_f16(af_h[i], bf_l[j], acc[i][j], 0, 0, 0);
            acc[i][j] = __builtin_amdgcn_mfma_f32_32x32x16_f16(af_l[i], bf_h[j], acc[i][j], 0, 0, 0);
          }
      }
    }

    // C/D (32x32): col = lane&31, row = (r&3)+8*(r>>2)+4*half
    float bb[2];
    int gc[2];
#pragma unroll
    for (int j = 0; j < 2; ++j) {
      gc[j] = n0 + wc * 64 + j * 32 + l31;
      bb[j] = bias[gc[j]];
    }
    if constexpr (MODE == 0) {
#pragma unroll
      for (int i = 0; i < 2; ++i)
#pragma unroll
        for (int r = 0; r < 16; ++r) {
          const int row = m0 + wr * 64 + i * 32 + (r & 3) + 8 * (r >> 2) + 4 * half;
#pragma unroll
          for (int j = 0; j < 2; ++j)
            outF[(size_t)row * NTOT + gc[j]] = acc[i][j][r] * INVS + bb[j];
        }
    } else if constexpr (MODE == 1) {
#pragma unroll
      for (int i = 0; i < 2; ++i)
#pragma unroll
        for (int r = 0; r < 16; ++r) {
          const int row = m0 + wr * 64 + i * 32 + (r & 3) + 8 * (r >> 2) + 4 * half;
#pragma unroll
          for (int j = 0; j < 2; ++j) {
            float v = fmaxf(acc[i][j][r] * INVS + bb[j], 0.f) * SCA;
            _Float16 hh, ll;
            fsplit(v, hh, ll);
            outHh[(size_t)row * NTOT + gc[j]] = hh;
            outHl[(size_t)row * NTOT + gc[j]] = ll;
          }
        }
    } else {
      const int slot = blockIdx.y * 2 + wc;   // 32 col-slots of 64
#pragma unroll
      for (int i = 0; i < 2; ++i)
#pragma unroll
        for (int r = 0; r < 16; ++r) {
          float v0 = acc[i][0][r] * INVS + bb[0];
          float v1 = acc[i][1][r] * INVS + bb[1];
          float M;
          int I;
          if (v0 >= v1) { M = v0; I = gc[0]; }
          else          { M = v1; I = gc[1]; }
#pragma unroll
          for (int sh = 1; sh <= 16; sh <<= 1) {
            float M2 = __shfl_xor(M, sh);
            int   I2 = __shfl_xor(I, sh);
            if (M2 > M || (M2 == M && I2 < I)) { M = M2; I = I2; }
          }
          if (l31 == 0) {
            const int grow = m0 + wr * 64 + i * 32 + (r & 3) + 8 * (r >> 2) + 4 * half;
            pM[(size_t)slot * pstr + grow] = M;
            pI[(size_t)slot * pstr + grow] = (float)I;
          }
        }
    }
  }
}

// ---------------- approx GEMM (hh only), m97 geometry ----------------
// 128x128 tile, BK=32, mfma_f32_16x16x32_f16, 4 waves 2x2, 4x4 frags/wave.
// One b128 frag spans the full BK=32 (k = q*8+j) -> 8 frag-reads per 16 MFMAs.
// Epilogue: per-row online (max, 2nd-max, first-argmax, sumexp) -> 32 col-slots
// of 64, stride astr (chunk-local rows).
__global__ __launch_bounds__(256) void gemm_approx(
    const _Float16* __restrict__ Ah, const _Float16* __restrict__ Bh,
    const float* __restrict__ bias,
    float* __restrict__ pM, float* __restrict__ pM2,
    float* __restrict__ pS, int* __restrict__ pI, int astr) {
  __shared__ __align__(16) _Float16 sAll[8192];   // A[128][32] | B[128][32]
  const int t = threadIdx.x;
  const int lane = t & 63;
  const int wv = t >> 6;
  const int wr = wv & 1, wc = wv >> 1;
  const int q = lane >> 4, l16 = lane & 15;
  const int m0 = blockIdx.x << 7;
  const int n0 = blockIdx.y << 7;

  // staging sources: 1024 16B chunks (A 512 | B 512), 4 gld16 per thread
  const _Float16* src0[4];
#pragma unroll
  for (int it = 0; it < 4; ++it) {
    int p = it * 256 + t;
    int row = (p & 511) >> 2;
    int cp = p & 3;
    int sw = ((row >> 1) ^ (row >> 3)) & 3;
    const _Float16* base = (p < 512) ? (Ah + (size_t)(m0 + row) * HHD)
                                     : (Bh + (size_t)(n0 + row) * HHD);
    src0[it] = base + ((cp ^ sw) << 3);
  }
  _Float16* dstw = sAll + (size_t)(wv * 64) * 8;   // wave-uniform DMA dest

  // frag-read offsets (halfs): row-local swizzle matches the staging side
  int offA[4], offB[4];
#pragma unroll
  for (int i = 0; i < 4; ++i) {
    int ra = wr * 64 + i * 16 + l16;
    int swa = ((ra >> 1) ^ (ra >> 3)) & 3;
    offA[i] = ra * 32 + ((q ^ swa) << 3);
    int rb = wc * 64 + i * 16 + l16;
    int swb = ((rb >> 1) ^ (rb >> 3)) & 3;
    offB[i] = 4096 + rb * 32 + ((q ^ swb) << 3);
  }

  f4 acc[4][4] = {};
  for (int k0 = 0; k0 < HHD; k0 += 32) {
    __syncthreads();
#pragma unroll
    for (int it = 0; it < 4; ++it)
      gld16(src0[it] + k0, dstw + it * 2048);
    __syncthreads();
    h8 af[4], bf[4];
#pragma unroll
    for (int i = 0; i < 4; ++i) af[i] = *(const h8*)&sAll[offA[i]];
#pragma unroll
    for (int j = 0; j < 4; ++j) bf[j] = *(const h8*)&sAll[offB[j]];
#pragma unroll
    for (int j = 0; j < 4; ++j)
#pragma unroll
      for (int i = 0; i < 4; ++i)
        acc[i][j] = __builtin_amdgcn_mfma_f32_16x16x32_f16(af[i], bf[j], acc[i][j], 0, 0, 0);
  }

  // epilogue; C/D 16x16: row = q*4+rr, col = l16 (verified round-1 layout)
  const int slot = blockIdx.y * 2 + wc;   // 32 slots of 64 cols
  float bb[4];
  int gc[4];
#pragma unroll
  for (int j = 0; j < 4; ++j) {
    gc[j] = n0 + wc * 64 + j * 16 + l16;
    bb[j] = bias[gc[j]];
  }
#pragma unroll
  for (int i = 0; i < 4; ++i)
#pragma unroll
    for (int rr = 0; rr < 4; ++rr) {
      float M = acc[i][0][rr] * INVS + bb[0], M2 = -INFINITY, S = 1.f;
      int I = gc[0];
#pragma unroll
      for (int j = 1; j < 4; ++j) {
        float v = acc[i][j][rr] * INVS + bb[j];
        if (v > M || (v == M && gc[j] < I)) {
          S = S * __expf(M - v) + 1.f; M2 = M; M = v; I = gc[j];
        } else {
          S += __expf(v - M); M2 = fmaxf(M2, v);
        }
      }
#pragma unroll
      for (int sh = 1; sh <= 8; sh <<= 1) {   // reduce across the 16-lane group
        float Mo = __shfl_xor(M, sh);
        float M2o = __shfl_xor(M2, sh);
        float So = __shfl_xor(S, sh);
        int   Io = __shfl_xor(I, sh);
        if (Mo > M || (Mo == M && Io < I)) {
          S = S * __expf(M - Mo) + So; M2 = fmaxf(M, M2o); M = Mo; I = Io;
        } else {
          S += So * __expf(Mo - M); M2 = fmaxf(M2, Mo);
        }
      }
      if (l16 == 0) {
        const int grow = m0 + wr * 64 + i * 16 + q * 4 + rr;
        pM[(size_t)slot * astr + grow] = M;
        pM2[(size_t)slot * astr + grow] = M2;
        pS[(size_t)slot * astr + grow] = S;
        pI[(size_t)slot * astr + grow] = I;
      }
    }
}

// -------- flag: merge 32 approx slots; emit m/i; flag small gaps ----
__global__ void flag_k(const float* __restrict__ pM, const float* __restrict__ pM2,
                       const float* __restrict__ pS, const int* __restrict__ pI,
                       int astr, int rows,
                       float* __restrict__ map, int* __restrict__ iap, int row0,
                       int* __restrict__ list, int* __restrict__ cnt) {
  int r = blockIdx.x * 256 + threadIdx.x;
  if (r >= rows) return;
  float M = pM[r], M2 = pM2[r], S = pS[r];
  int I = pI[r];
  for (int s = 1; s < 32; ++s) {
    size_t o = (size_t)s * astr + r;
    float m = pM[o], m2 = pM2[o], ss = pS[o];
    int ii = pI[o];
    if (m > M || (m == M && ii < I)) {
      M2 = fmaxf(M, m2); S = S * __expf(M - m) + ss; M = m; I = ii;
    } else {
      M2 = fmaxf(M2, m); S += ss * __expf(m - M);
    }
  }
  map[row0 + r] = 1.f / S;
  iap[row0 + r] = I;
  if (M - M2 < MARGIN) {
    int c = atomicAdd(cnt, 1);
    if (c < CAPR) list[c] = r;   // chunk-local row
  }
}

// -------- gather flagged H rows (exact split) into dense rescue buffer ------
__global__ void gather_k(const _Float16* __restrict__ Hh, const _Float16* __restrict__ Hl,
                         const int* __restrict__ list, const int* __restrict__ cnt,
                         _Float16* __restrict__ Gh, _Float16* __restrict__ Gl) {
  int b = blockIdx.x;
  int active = *cnt;
  if (active > CAPR) active = CAPR;
  if (b >= active) return;
  int r = list[b];
  int t = threadIdx.x;   // 128 threads x 8 halfs = 1024
  *(h8*)(Gh + (size_t)b * HHD + t * 8) = *(const h8*)(Hh + (size_t)r * HHD + t * 8);
  *(h8*)(Gl + (size_t)b * HHD + t * 8) = *(const h8*)(Hl + (size_t)r * HHD + t * 8);
}

// -------- rescue merge: exact argmax over 32 slots -> overwrite iap ---------
__global__ void rescue_merge(const float* __restrict__ pMr, const float* __restrict__ pIr,
                             const int* __restrict__ list, const int* __restrict__ cnt,
                             int* __restrict__ iap, int row0) {
  int c = blockIdx.x * 256 + threadIdx.x;
  int a = *cnt;
  if (a > CAPR) a = CAPR;
  if (c >= a) return;
  float M = pMr[c];
  int I = (int)pIr[c];
  for (int s = 1; s < 32; ++s) {
    size_t o = (size_t)s * CAPR + c;
    float m = pMr[o];
    int i2 = (int)pIr[o];
    if (m > M || (m == M && i2 < I)) { M = m; I = i2; }
  }
  iap[row0 + list[c]] = I;
}

// ------- ln_dual: one pass over A+X -> both step activations, split --------
__global__ __launch_bounds__(256) void ln_dual(
    const float* __restrict__ A, const float* __restrict__ X,
    const float* __restrict__ na,
    _Float16* __restrict__ y0h, _Float16* __restrict__ y0l,
    _Float16* __restrict__ y1h, _Float16* __restrict__ y1l) {
  int t = threadIdx.x;
  int lane = t & 63;
  int w = t >> 6;
  int r = blockIdx.x * 4 + w;
  const float* ap = A + (size_t)r * DD + lane * 8;
  const float* xp = X + (size_t)r * DD + lane * 8;
  const float* np = na + lane * 8;
  float v0[8], v1[8];
  float s0 = 0.f, q0 = 0.f, s1 = 0.f, q1 = 0.f;
#pragma unroll
  for (int i = 0; i < 8; ++i) {
    float a = ap[i];
    v0[i] = a + np[i];
    v1[i] = a + xp[i];
    s0 += v0[i]; q0 += v0[i] * v0[i];
    s1 += v1[i]; q1 += v1[i] * v1[i];
  }
#pragma unroll
  for (int m = 1; m <= 32; m <<= 1) {
    s0 += __shfl_xor(s0, m); q0 += __shfl_xor(q0, m);
    s1 += __shfl_xor(s1, m); q1 += __shfl_xor(q1, m);
  }
  float mu0 = s0 * (1.f / DD), mu1 = s1 * (1.f / DD);
  float rs0 = 1.f / sqrtf(q0 * (1.f / DD) - mu0 * mu0 + 1e-5f);
  float rs1 = 1.f / sqrtf(q1 * (1.f / DD) - mu1 * mu1 + 1e-5f);
  _Float16 h0[8], l0[8], h1[8], l1[8];
#pragma unroll
  for (int i = 0; i < 8; ++i) {
    fsplit((v0[i] - mu0) * rs0 * SCA, h0[i], l0[i]);
    fsplit((v1[i] - mu1) * rs1 * SCA, h1[i], l1[i]);
  }
  *(h8*)(y0h + (size_t)r * DD + lane * 8) = *(h8*)h0;
  *(h8*)(y0l + (size_t)r * DD + lane * 8) = *(h8*)l0;
  *(h8*)(y1h + (size_t)r * DD + lane * 8) = *(h8*)h1;
  *(h8*)(y1l + (size_t)r * DD + lane * 8) = *(h8*)l1;
}

// ---------------- finalize ----------------
__global__ void finalize_k(const float* __restrict__ map0, const int* __restrict__ iap0,
                           const float* __restrict__ map1, const int* __restrict__ iap1,
                           float* __restrict__ out) {
  int r = blockIdx.x * 256 + threadIdx.x;
  float m0v = map0[r], m1v = map1[r];
  int i0v = iap0[r], i1v = iap1[r];
  bool c0 = (i0v != 0) && (m0v >= 0.1f);
  bool c1 = c0 && (i1v != 0) && (m1v >= 0.1f);
  out[r] = c0 ? (c1 ? m0v * m1v : m0v) : 0.f;
  out[MTOT + r] = (float)i0v;
  out[2 * MTOT + r] = (float)i1v;
  out[3 * MTOT + r] = (float)((c0 ? 1 : 0) + (c1 ? 1 : 0));
}

// ---------------- host ----------------
extern "C" void kernel_launch(void* const* d_in, const int* in_sizes, int n_in,
                              void* d_out, int out_size, void* d_ws, size_t ws_size,
                              hipStream_t stream) {
  const float* X   = (const float*)d_in[0];
  const float* na  = (const float*)d_in[1];
  const float* vw  = (const float*)d_in[2];
  const float* vb  = (const float*)d_in[3];
  const float* ow  = (const float*)d_in[4];
  const float* ob  = (const float*)d_in[5];
  const float* lng = (const float*)d_in[6];
  const float* lnb = (const float*)d_in[7];
  const float* w1  = (const float*)d_in[8];
  const float* b1  = (const float*)d_in[9];
  const float* w2  = (const float*)d_in[10];
  const float* b2  = (const float*)d_in[11];
  float* out = (float*)d_out;

  char* p = (char*)d_ws;
  auto alloc = [&](size_t bytes) -> void* {
    void* r = (void*)p;
    p += (bytes + 255) & ~(size_t)255;
    return r;
  };
  // ---- fixed allocations (~30 MB) ----
  _Float16* wvo_h = (_Float16*)alloc(512 * 512 * 2);
  _Float16* wvo_l = (_Float16*)alloc(512 * 512 * 2);
  float*    cvec  = (float*)alloc(512 * 4);
  _Float16* w1p_h = (_Float16*)alloc(1024 * 512 * 2);
  _Float16* w1p_l = (_Float16*)alloc(1024 * 512 * 2);
  float*    b1p   = (float*)alloc(1024 * 4);
  _Float16* w2_h  = (_Float16*)alloc(2048 * 1024 * 2);
  _Float16* w2_l  = (_Float16*)alloc(2048 * 1024 * 2);
  float* map0 = (float*)alloc((size_t)MTOT * 4);
  float* map1 = (float*)alloc((size_t)MTOT * 4);
  int* iap0 = (int*)alloc((size_t)MTOT * 4);
  int* iap1 = (int*)alloc((size_t)MTOT * 4);
  int* list = (int*)alloc(CAPR * 4);
  int* cnt  = (int*)alloc(512 * 4);   // per-(chunk,step) counters
  float* pMr = (float*)alloc((size_t)32 * CAPR * 4);
  float* pIr = (float*)alloc((size_t)32 * CAPR * 4);
  _Float16* Gh = (_Float16*)alloc((size_t)CAPR * HHD * 2);
  _Float16* Gl = (_Float16*)alloc((size_t)CAPR * HHD * 2);

  // ---- chunk sizing: per-row bytes = xs 2048 + A 2048 + y0 2048 + H 4096
  //      + approx partials (32 slots x 16 B) 512 = 10752 ----
  size_t fixed = (size_t)(p - (char*)d_ws);
  size_t reserve = 2u << 20;
  size_t remain = ws_size > fixed + reserve ? ws_size - fixed - reserve : 0;
  int chunk = (int)(remain / 10752);
  chunk &= ~127;
  if (chunk < 128) chunk = 128;
  if (chunk > MTOT) chunk = MTOT;

  _Float16* xs_h = (_Float16*)alloc((size_t)chunk * 512 * 2);
  _Float16* xs_l = (_Float16*)alloc((size_t)chunk * 512 * 2);
  float*    Abuf = (float*)alloc((size_t)chunk * 512 * 4);
  _Float16* y0_h = (_Float16*)alloc((size_t)chunk * 512 * 2);
  _Float16* y0_l = (_Float16*)alloc((size_t)chunk * 512 * 2);
  _Float16* H_h  = (_Float16*)alloc((size_t)chunk * 1024 * 2);
  _Float16* H_l  = (_Float16*)alloc((size_t)chunk * 1024 * 2);
  float* pMa  = (float*)alloc((size_t)32 * chunk * 4);
  float* pM2a = (float*)alloc((size_t)32 * chunk * 4);
  float* pSa  = (float*)alloc((size_t)32 * chunk * 4);
  int*   pIa  = (int*)alloc((size_t)32 * chunk * 4);
  _Float16* y1_h = xs_h;   // alias: xs consumed by gemm1 before ln_dual writes
  _Float16* y1_l = xs_l;

  zero_cnt<<<2, 256, 0, stream>>>(cnt);
  prep_wvo_split<<<1024, 256, 0, stream>>>(vw, ow, wvo_h, wvo_l);
  prep_cvec<<<2, 256, 0, stream>>>(ow, vb, ob, cvec);
  prep_w1p_split<<<2048, 256, 0, stream>>>(w1, lng, w1p_h, w1p_l);
  prep_b1p<<<4, 256, 0, stream>>>(w1, lnb, b1, b1p);
  prep_w2_split<<<8192, 256, 0, stream>>>(w2, w2_h, w2_l);

  int citer = 0;
  for (int row0 = 0; row0 < MTOT; row0 += chunk, ++citer) {
    int rows = (MTOT - row0 < chunk) ? (MTOT - row0) : chunk;
    split_x<<<rows * 512 / 2048, 256, 0, stream>>>(X + (size_t)row0 * 512, xs_h, xs_l);
    gemm_split<0, 512, 512><<<dim3(rows / 128, 4), 256, 0, stream>>>(
        xs_h, xs_l, wvo_h, wvo_l, cvec, Abuf, nullptr, nullptr,
        nullptr, nullptr, nullptr, 0);
    ln_dual<<<rows / 4, 256, 0, stream>>>(Abuf, X + (size_t)row0 * 512, na,
                                          y0_h, y0_l, y1_h, y1_l);
    for (int s = 0; s < 2; ++s) {
      int* cp = cnt + citer * 2 + s;
      gemm_split<1, 512, 1024><<<dim3(rows / 128, 8), 256, 0, stream>>>(
          s == 0 ? y0_h : y1_h, s == 0 ? y0_l : y1_l, w1p_h, w1p_l, b1p,
          nullptr, H_h, H_l, nullptr, nullptr, nullptr, 0);
      gemm_approx<<<dim3(rows / 128, 16), 256, 0, stream>>>(
          H_h, w2_h, b2, pMa, pM2a, pSa, pIa, chunk);
      flag_k<<<(rows + 255) / 256, 256, 0, stream>>>(
          pMa, pM2a, pSa, pIa, chunk, rows,
          s == 0 ? map0 : map1, s == 0 ? iap0 : iap1, row0, list, cp);
      gather_k<<<CAPR, 128, 0, stream>>>(H_h, H_l, list, cp, Gh, Gl);
      gemm_split<2, 1024, 2048><<<dim3(8, 16), 256, 0, stream>>>(
          Gh, Gl, w2_h, w2_l, b2, nullptr, nullptr, nullptr,
          pMr, pIr, cp, CAPR);
      rescue_merge<<<CAPR / 256, 256, 0, stream>>>(
          pMr, pIr, list, cp, s == 0 ? iap0 : iap1, row0);
    }
  }
  finalize_k<<<MTOT / 256, 256, 0, stream>>>(map0, iap0, map1, iap1, out);
}

// Round 7
// 1476.697 us; speedup vs baseline: 4.0809x; 1.0775x over previous
//
#include <hip/hip_runtime.h>
#include <math.h>

#define MTOT 32768   // B*R
#define DD   512
#define HHD  1024
#define NRELN 2048
#define SCA  64.f          // activation fp16 pre-scale
#define SCB  1024.f        // weight fp16 pre-scale
#define INVS (1.f / 65536.f)
#define CAPR 4096          // rescue row capacity (expected ~1300/step)
#define MARGIN 2.0e-3f     // approx-gap rescue threshold (~50 sigma of approx err)

typedef _Float16 h8  __attribute__((ext_vector_type(8)));
typedef float    f4  __attribute__((ext_vector_type(4)));
typedef float    f16v __attribute__((ext_vector_type(16)));

__device__ __forceinline__ void fsplit(float x, _Float16& h, _Float16& l) {
  _Float16 t = (_Float16)x;
  h = t;
  l = (_Float16)(x - (float)t);   // hi/lo split: 2^-22 rel error total
}

__device__ __forceinline__ void gld16(const _Float16* g, _Float16* l) {
  __builtin_amdgcn_global_load_lds(
      (const __attribute__((address_space(1))) void*)g,
      (__attribute__((address_space(3))) void*)l, 16, 0, 0);
}

// ---------------- prep: fold + scale + split weights ----------------

__global__ void prep_wvo_split(const float* __restrict__ vw, const float* __restrict__ ow,
                               _Float16* __restrict__ wh, _Float16* __restrict__ wl) {
  int idx = blockIdx.x * 256 + threadIdx.x;   // 512*512
  int k = idx & 511;
  int n = idx >> 9;
  float s = 0.f;
  for (int j = 0; j < DD; ++j) s += ow[n * DD + j] * vw[j * DD + k];
  fsplit(s * SCB, wh[n * DD + k], wl[n * DD + k]);
}

__global__ void prep_cvec(const float* __restrict__ ow, const float* __restrict__ vb,
                          const float* __restrict__ ob, float* __restrict__ c) {
  int i = blockIdx.x * 256 + threadIdx.x;
  if (i < DD) {
    float s = ob[i];
    for (int k = 0; k < DD; ++k) s += ow[i * DD + k] * vb[k];
    c[i] = s;
  }
}

__global__ void prep_w1p_split(const float* __restrict__ w1, const float* __restrict__ g,
                               _Float16* __restrict__ wh, _Float16* __restrict__ wl) {
  int idx = blockIdx.x * 256 + threadIdx.x;   // 1024*512
  int k = idx & 511;
  int n = idx >> 9;
  fsplit(w1[n * DD + k] * g[k] * SCB, wh[n * DD + k], wl[n * DD + k]);
}

__global__ void prep_b1p(const float* __restrict__ w1, const float* __restrict__ lnb,
                         const float* __restrict__ b1, float* __restrict__ b1p) {
  int n = blockIdx.x * 256 + threadIdx.x;
  if (n < HHD) {
    float s = b1[n];
    for (int k = 0; k < DD; ++k) s += w1[n * DD + k] * lnb[k];
    b1p[n] = s;
  }
}

__global__ void prep_w2_split(const float* __restrict__ w2,
                              _Float16* __restrict__ wh, _Float16* __restrict__ wl) {
  int idx = blockIdx.x * 256 + threadIdx.x;   // 2048*1024
  int k = idx & 1023;
  int n = idx >> 10;
  fsplit(w2[n * HHD + k] * SCB, wh[n * HHD + k], wl[n * HHD + k]);
}

__global__ void split_x(const float* __restrict__ src, _Float16* __restrict__ h,
                        _Float16* __restrict__ l) {
  int idx = (blockIdx.x * 256 + threadIdx.x) * 8;
  float4 a = *(const float4*)(src + idx);
  float4 b = *(const float4*)(src + idx + 4);
  float vv[8] = {a.x, a.y, a.z, a.w, b.x, b.y, b.z, b.w};
  _Float16 hh[8], ll[8];
#pragma unroll
  for (int i = 0; i < 8; ++i) fsplit(vv[i] * SCA, hh[i], ll[i]);
  *(h8*)(h + idx) = *(h8*)hh;
  *(h8*)(l + idx) = *(h8*)ll;
}

__global__ void zero_cnt(int* c) { c[blockIdx.x * 256 + threadIdx.x] = 0; }

// ---------------- exact fp16-split GEMM (3-product), 128x128, BK=32 ----------
// SW(r) = ((r>>1)^(r>>3))&3 chunk swizzle.
// MODE 0: +bias -> fp32 out. MODE 1: +bias, relu, *SCA, split -> H.
// MODE 2: rescue rows (count from *cntp, grid-stride): per-row (max, argmax)
//         -> pM/pI partials (32 col-slots), stride pstr.
template <int MODE, int KDIM, int NTOT>
__global__ __launch_bounds__(256) void gemm_split(
    const _Float16* __restrict__ Ah, const _Float16* __restrict__ Al,
    const _Float16* __restrict__ Bh, const _Float16* __restrict__ Bl,
    const float* __restrict__ bias,
    float* __restrict__ outF,
    _Float16* __restrict__ outHh, _Float16* __restrict__ outHl,
    float* __restrict__ pM, float* __restrict__ pI,
    const int* __restrict__ cntp, int pstr) {
  __shared__ __align__(16) _Float16 sA[2][128][32];
  __shared__ __align__(16) _Float16 sB[2][128][32];
  const int t = threadIdx.x;
  const int lane = t & 63;
  const int wv = t >> 6;
  const int wr = wv & 1, wc = wv >> 1;
  const int l31 = lane & 31, half = lane >> 5;
  const int n0 = blockIdx.y << 7;

  const _Float16* gsp = (wv == 0) ? Ah : (wv == 1) ? Al : (wv == 2) ? Bh : Bl;
  _Float16* lbase = (wv == 0) ? &sA[0][0][0] : (wv == 1) ? &sA[1][0][0]
                  : (wv == 2) ? &sB[0][0][0] : &sB[1][0][0];
  const int srow = lane >> 2;
  const int scp = lane & 3;
  const int swzE = ((srow >> 1) & 3) ^ ((srow >> 3) & 1);
  const int swzO = swzE ^ 2;
  const int swz = ((l31 >> 1) ^ (l31 >> 3)) & 3;   // frag-read side

  int nmb;
  if constexpr (MODE == 2) {
    int a = *cntp;
    if (a > CAPR) a = CAPR;
    nmb = (a + 127) >> 7;
  } else {
    nmb = gridDim.x;
  }

  for (int mb = blockIdx.x; mb < nmb; mb += gridDim.x) {
    const int m0 = mb << 7;
    const int gb = (wv < 2) ? m0 : n0;
    const _Float16* gA0 = gsp + (size_t)(gb + srow) * KDIM + ((scp ^ swzE) << 3);
    const _Float16* gA1 = gsp + (size_t)(gb + srow) * KDIM + ((scp ^ swzO) << 3);

    f16v acc[2][2] = {};
    for (int k0 = 0; k0 < KDIM; k0 += 32) {
      __syncthreads();
#pragma unroll
      for (int it = 0; it < 8; ++it)
        gld16(((it & 1) ? gA1 : gA0) + (size_t)(it * 16) * KDIM + k0, lbase + it * 512);
      __syncthreads();
#pragma unroll
      for (int ks = 0; ks < 2; ++ks) {
        const int pos = (((ks << 1) + half) ^ swz) << 3;
        h8 af_h[2], af_l[2], bf_h[2], bf_l[2];
#pragma unroll
        for (int i = 0; i < 2; ++i) {
          const int mr = wr * 64 + i * 32 + l31;
          af_h[i] = *(const h8*)&sA[0][mr][pos];
          af_l[i] = *(const h8*)&sA[1][mr][pos];
        }
#pragma unroll
        for (int j = 0; j < 2; ++j) {
          const int nr = wc * 64 + j * 32 + l31;
          bf_h[j] = *(const h8*)&sB[0][nr][pos];
          bf_l[j] = *(const h8*)&sB[1][nr][pos];
        }
#pragma unroll
        for (int j = 0; j < 2; ++j)
#pragma unroll
          for (int i = 0; i < 2; ++i) {
            acc[i][j] = __builtin_amdgcn_mfma_f32_32x32x16_f16(af_h[i], bf_h[j], acc[i][j], 0, 0, 0);
            acc[i][j] = __builtin_amdgcn_mfma_f32_32x32x16_f16(af_h[i], bf_l[j], acc[i][j], 0, 0, 0);
            acc[i][j] = __builtin_amdgcn_mfma_f32_32x32x16_f16(af_l[i], bf_h[j], acc[i][j], 0, 0, 0);
          }
      }
    }

    // C/D (32x32): col = lane&31, row = (r&3)+8*(r>>2)+4*half
    float bb[2];
    int gc[2];
#pragma unroll
    for (int j = 0; j < 2; ++j) {
      gc[j] = n0 + wc * 64 + j * 32 + l31;
      bb[j] = bias[gc[j]];
    }
    if constexpr (MODE == 0) {
#pragma unroll
      for (int i = 0; i < 2; ++i)
#pragma unroll
        for (int r = 0; r < 16; ++r) {
          const int row = m0 + wr * 64 + i * 32 + (r & 3) + 8 * (r >> 2) + 4 * half;
#pragma unroll
          for (int j = 0; j < 2; ++j)
            outF[(size_t)row * NTOT + gc[j]] = acc[i][j][r] * INVS + bb[j];
        }
    } else if constexpr (MODE == 1) {
#pragma unroll
      for (int i = 0; i < 2; ++i)
#pragma unroll
        for (int r = 0; r < 16; ++r) {
          const int row = m0 + wr * 64 + i * 32 + (r & 3) + 8 * (r >> 2) + 4 * half;
#pragma unroll
          for (int j = 0; j < 2; ++j) {
            float v = fmaxf(acc[i][j][r] * INVS + bb[j], 0.f) * SCA;
            _Float16 hh, ll;
            fsplit(v, hh, ll);
            outHh[(size_t)row * NTOT + gc[j]] = hh;
            outHl[(size_t)row * NTOT + gc[j]] = ll;
          }
        }
    } else {
      const int slot = blockIdx.y * 2 + wc;   // 32 col-slots of 64
#pragma unroll
      for (int i = 0; i < 2; ++i)
#pragma unroll
        for (int r = 0; r < 16; ++r) {
          float v0 = acc[i][0][r] * INVS + bb[0];
          float v1 = acc[i][1][r] * INVS + bb[1];
          float M;
          int I;
          if (v0 >= v1) { M = v0; I = gc[0]; }
          else          { M = v1; I = gc[1]; }
#pragma unroll
          for (int sh = 1; sh <= 16; sh <<= 1) {
            float M2 = __shfl_xor(M, sh);
            int   I2 = __shfl_xor(I, sh);
            if (M2 > M || (M2 == M && I2 < I)) { M = M2; I = I2; }
          }
          if (l31 == 0) {
            const int grow = m0 + wr * 64 + i * 32 + (r & 3) + 8 * (r >> 2) + 4 * half;
            pM[(size_t)slot * pstr + grow] = M;
            pI[(size_t)slot * pstr + grow] = (float)I;
          }
        }
    }
  }
}

// ---------------- approx GEMM (hh only), m97 geometry, XCD-swizzled --------
// 128x128 tile, BK=32, mfma_f32_16x16x32_f16, 4 waves 2x2, 4x4 frags/wave.
// Grid dim3(8, mblocks*2): n_blk = x*2 + (y&1), m_blk = y>>1. Linear dispatch
// is x-fastest -> each XCD (round-robin by linear id) sticks to one 2-n-tile
// group: B slab 512 KB stays L2-resident; paired n-tiles reuse the A tile.
// Epilogue: per-row online (max, 2nd-max, first-argmax, sumexp) -> 32
// col-slots of 64, stride astr (chunk-local rows).
__global__ __launch_bounds__(256) void gemm_approx(
    const _Float16* __restrict__ Ah, const _Float16* __restrict__ Bh,
    const float* __restrict__ bias,
    float* __restrict__ pM, float* __restrict__ pM2,
    float* __restrict__ pS, int* __restrict__ pI, int astr) {
  __shared__ __align__(16) _Float16 sAll[8192];   // A[128][32] | B[128][32]
  const int t = threadIdx.x;
  const int lane = t & 63;
  const int wv = t >> 6;
  const int wr = wv & 1, wc = wv >> 1;
  const int q = lane >> 4, l16 = lane & 15;
  const int nb = blockIdx.x * 2 + (blockIdx.y & 1);   // n-tile 0..15
  const int mb = blockIdx.y >> 1;
  const int m0 = mb << 7;
  const int n0 = nb << 7;

  // staging sources: 1024 16B chunks (A 512 | B 512), 4 gld16 per thread
  const _Float16* src0[4];
#pragma unroll
  for (int it = 0; it < 4; ++it) {
    int p = it * 256 + t;
    int row = (p & 511) >> 2;
    int cp = p & 3;
    int sw = ((row >> 1) ^ (row >> 3)) & 3;
    const _Float16* base = (p < 512) ? (Ah + (size_t)(m0 + row) * HHD)
                                     : (Bh + (size_t)(n0 + row) * HHD);
    src0[it] = base + ((cp ^ sw) << 3);
  }
  _Float16* dstw = sAll + (size_t)(wv * 64) * 8;   // wave-uniform DMA dest

  // frag-read offsets (halfs): row-local swizzle matches the staging side
  int offA[4], offB[4];
#pragma unroll
  for (int i = 0; i < 4; ++i) {
    int ra = wr * 64 + i * 16 + l16;
    int swa = ((ra >> 1) ^ (ra >> 3)) & 3;
    offA[i] = ra * 32 + ((q ^ swa) << 3);
    int rb = wc * 64 + i * 16 + l16;
    int swb = ((rb >> 1) ^ (rb >> 3)) & 3;
    offB[i] = 4096 + rb * 32 + ((q ^ swb) << 3);
  }

  f4 acc[4][4] = {};
  for (int k0 = 0; k0 < HHD; k0 += 32) {
    __syncthreads();
#pragma unroll
    for (int it = 0; it < 4; ++it)
      gld16(src0[it] + k0, dstw + it * 2048);
    __syncthreads();
    h8 af[4], bf[4];
#pragma unroll
    for (int i = 0; i < 4; ++i) af[i] = *(const h8*)&sAll[offA[i]];
#pragma unroll
    for (int j = 0; j < 4; ++j) bf[j] = *(const h8*)&sAll[offB[j]];
#pragma unroll
    for (int j = 0; j < 4; ++j)
#pragma unroll
      for (int i = 0; i < 4; ++i)
        acc[i][j] = __builtin_amdgcn_mfma_f32_16x16x32_f16(af[i], bf[j], acc[i][j], 0, 0, 0);
  }

  // epilogue; C/D 16x16: row = q*4+rr, col = l16 (verified round-1 layout)
  const int slot = nb * 2 + wc;   // 32 slots of 64 cols
  float bb[4];
  int gc[4];
#pragma unroll
  for (int j = 0; j < 4; ++j) {
    gc[j] = n0 + wc * 64 + j * 16 + l16;
    bb[j] = bias[gc[j]];
  }
#pragma unroll
  for (int i = 0; i < 4; ++i)
#pragma unroll
    for (int rr = 0; rr < 4; ++rr) {
      float M = acc[i][0][rr] * INVS + bb[0], M2 = -INFINITY, S = 1.f;
      int I = gc[0];
#pragma unroll
      for (int j = 1; j < 4; ++j) {
        float v = acc[i][j][rr] * INVS + bb[j];
        if (v > M || (v == M && gc[j] < I)) {
          S = S * __expf(M - v) + 1.f; M2 = M; M = v; I = gc[j];
        } else {
          S += __expf(v - M); M2 = fmaxf(M2, v);
        }
      }
#pragma unroll
      for (int sh = 1; sh <= 8; sh <<= 1) {   // reduce across the 16-lane group
        float Mo = __shfl_xor(M, sh);
        float M2o = __shfl_xor(M2, sh);
        float So = __shfl_xor(S, sh);
        int   Io = __shfl_xor(I, sh);
        if (Mo > M || (Mo == M && Io < I)) {
          S = S * __expf(M - Mo) + So; M2 = fmaxf(M, M2o); M = Mo; I = Io;
        } else {
          S += So * __expf(Mo - M); M2 = fmaxf(M2, Mo);
        }
      }
      if (l16 == 0) {
        const int grow = m0 + wr * 64 + i * 16 + q * 4 + rr;
        pM[(size_t)slot * astr + grow] = M;
        pM2[(size_t)slot * astr + grow] = M2;
        pS[(size_t)slot * astr + grow] = S;
        pI[(size_t)slot * astr + grow] = I;
      }
    }
}

// -------- flag: merge 32 approx slots; emit m/i; flag small gaps ----
__global__ void flag_k(const float* __restrict__ pM, const float* __restrict__ pM2,
                       const float* __restrict__ pS, const int* __restrict__ pI,
                       int astr, int rows,
                       float* __restrict__ map, int* __restrict__ iap, int row0,
                       int* __restrict__ list, int* __restrict__ cnt) {
  int r = blockIdx.x * 256 + threadIdx.x;
  if (r >= rows) return;
  float M = pM[r], M2 = pM2[r], S = pS[r];
  int I = pI[r];
  for (int s = 1; s < 32; ++s) {
    size_t o = (size_t)s * astr + r;
    float m = pM[o], m2 = pM2[o], ss = pS[o];
    int ii = pI[o];
    if (m > M || (m == M && ii < I)) {
      M2 = fmaxf(M, m2); S = S * __expf(M - m) + ss; M = m; I = ii;
    } else {
      M2 = fmaxf(M2, m); S += ss * __expf(m - M);
    }
  }
  map[row0 + r] = 1.f / S;
  iap[row0 + r] = I;
  if (M - M2 < MARGIN) {
    int c = atomicAdd(cnt, 1);
    if (c < CAPR) list[c] = r;   // chunk-local row
  }
}

// -------- gather flagged H rows (exact split) into dense rescue buffer ------
__global__ void gather_k(const _Float16* __restrict__ Hh, const _Float16* __restrict__ Hl,
                         const int* __restrict__ list, const int* __restrict__ cnt,
                         _Float16* __restrict__ Gh, _Float16* __restrict__ Gl) {
  int b = blockIdx.x;
  int active = *cnt;
  if (active > CAPR) active = CAPR;
  if (b >= active) return;
  int r = list[b];
  int t = threadIdx.x;   // 128 threads x 8 halfs = 1024
  *(h8*)(Gh + (size_t)b * HHD + t * 8) = *(const h8*)(Hh + (size_t)r * HHD + t * 8);
  *(h8*)(Gl + (size_t)b * HHD + t * 8) = *(const h8*)(Hl + (size_t)r * HHD + t * 8);
}

// -------- rescue merge: exact argmax over 32 slots -> overwrite iap ---------
__global__ void rescue_merge(const float* __restrict__ pMr, const float* __restrict__ pIr,
                             const int* __restrict__ list, const int* __restrict__ cnt,
                             int* __restrict__ iap, int row0) {
  int c = blockIdx.x * 256 + threadIdx.x;
  int a = *cnt;
  if (a > CAPR) a = CAPR;
  if (c >= a) return;
  float M = pMr[c];
  int I = (int)pIr[c];
  for (int s = 1; s < 32; ++s) {
    size_t o = (size_t)s * CAPR + c;
    float m = pMr[o];
    int i2 = (int)pIr[o];
    if (m > M || (m == M && i2 < I)) { M = m; I = i2; }
  }
  iap[row0 + list[c]] = I;
}

// ------- ln_dual: one pass over A+X -> both step activations, split --------
__global__ __launch_bounds__(256) void ln_dual(
    const float* __restrict__ A, const float* __restrict__ X,
    const float* __restrict__ na,
    _Float16* __restrict__ y0h, _Float16* __restrict__ y0l,
    _Float16* __restrict__ y1h, _Float16* __restrict__ y1l) {
  int t = threadIdx.x;
  int lane = t & 63;
  int w = t >> 6;
  int r = blockIdx.x * 4 + w;
  const float* ap = A + (size_t)r * DD + lane * 8;
  const float* xp = X + (size_t)r * DD + lane * 8;
  const float* np = na + lane * 8;
  float v0[8], v1[8];
  float s0 = 0.f, q0 = 0.f, s1 = 0.f, q1 = 0.f;
#pragma unroll
  for (int i = 0; i < 8; ++i) {
    float a = ap[i];
    v0[i] = a + np[i];
    v1[i] = a + xp[i];
    s0 += v0[i]; q0 += v0[i] * v0[i];
    s1 += v1[i]; q1 += v1[i] * v1[i];
  }
#pragma unroll
  for (int m = 1; m <= 32; m <<= 1) {
    s0 += __shfl_xor(s0, m); q0 += __shfl_xor(q0, m);
    s1 += __shfl_xor(s1, m); q1 += __shfl_xor(q1, m);
  }
  float mu0 = s0 * (1.f / DD), mu1 = s1 * (1.f / DD);
  float rs0 = 1.f / sqrtf(q0 * (1.f / DD) - mu0 * mu0 + 1e-5f);
  float rs1 = 1.f / sqrtf(q1 * (1.f / DD) - mu1 * mu1 + 1e-5f);
  _Float16 h0[8], l0[8], h1[8], l1[8];
#pragma unroll
  for (int i = 0; i < 8; ++i) {
    fsplit((v0[i] - mu0) * rs0 * SCA, h0[i], l0[i]);
    fsplit((v1[i] - mu1) * rs1 * SCA, h1[i], l1[i]);
  }
  *(h8*)(y0h + (size_t)r * DD + lane * 8) = *(h8*)h0;
  *(h8*)(y0l + (size_t)r * DD + lane * 8) = *(h8*)l0;
  *(h8*)(y1h + (size_t)r * DD + lane * 8) = *(h8*)h1;
  *(h8*)(y1l + (size_t)r * DD + lane * 8) = *(h8*)l1;
}

// ---------------- finalize ----------------
__global__ void finalize_k(const float* __restrict__ map0, const int* __restrict__ iap0,
                           const float* __restrict__ map1, const int* __restrict__ iap1,
                           float* __restrict__ out) {
  int r = blockIdx.x * 256 + threadIdx.x;
  float m0v = map0[r], m1v = map1[r];
  int i0v = iap0[r], i1v = iap1[r];
  bool c0 = (i0v != 0) && (m0v >= 0.1f);
  bool c1 = c0 && (i1v != 0) && (m1v >= 0.1f);
  out[r] = c0 ? (c1 ? m0v * m1v : m0v) : 0.f;
  out[MTOT + r] = (float)i0v;
  out[2 * MTOT + r] = (float)i1v;
  out[3 * MTOT + r] = (float)((c0 ? 1 : 0) + (c1 ? 1 : 0));
}

// ---------------- host ----------------
extern "C" void kernel_launch(void* const* d_in, const int* in_sizes, int n_in,
                              void* d_out, int out_size, void* d_ws, size_t ws_size,
                              hipStream_t stream) {
  const float* X   = (const float*)d_in[0];
  const float* na  = (const float*)d_in[1];
  const float* vw  = (const float*)d_in[2];
  const float* vb  = (const float*)d_in[3];
  const float* ow  = (const float*)d_in[4];
  const float* ob  = (const float*)d_in[5];
  const float* lng = (const float*)d_in[6];
  const float* lnb = (const float*)d_in[7];
  const float* w1  = (const float*)d_in[8];
  const float* b1  = (const float*)d_in[9];
  const float* w2  = (const float*)d_in[10];
  const float* b2  = (const float*)d_in[11];
  float* out = (float*)d_out;

  char* p = (char*)d_ws;
  auto alloc = [&](size_t bytes) -> void* {
    void* r = (void*)p;
    p += (bytes + 255) & ~(size_t)255;
    return r;
  };
  // ---- fixed allocations (~30 MB) ----
  _Float16* wvo_h = (_Float16*)alloc(512 * 512 * 2);
  _Float16* wvo_l = (_Float16*)alloc(512 * 512 * 2);
  float*    cvec  = (float*)alloc(512 * 4);
  _Float16* w1p_h = (_Float16*)alloc(1024 * 512 * 2);
  _Float16* w1p_l = (_Float16*)alloc(1024 * 512 * 2);
  float*    b1p   = (float*)alloc(1024 * 4);
  _Float16* w2_h  = (_Float16*)alloc(2048 * 1024 * 2);
  _Float16* w2_l  = (_Float16*)alloc(2048 * 1024 * 2);
  float* map0 = (float*)alloc((size_t)MTOT * 4);
  float* map1 = (float*)alloc((size_t)MTOT * 4);
  int* iap0 = (int*)alloc((size_t)MTOT * 4);
  int* iap1 = (int*)alloc((size_t)MTOT * 4);
  int* list = (int*)alloc(CAPR * 4);
  int* cnt  = (int*)alloc(512 * 4);   // per-(chunk,step) counters
  float* pMr = (float*)alloc((size_t)32 * CAPR * 4);
  float* pIr = (float*)alloc((size_t)32 * CAPR * 4);
  _Float16* Gh = (_Float16*)alloc((size_t)CAPR * HHD * 2);
  _Float16* Gl = (_Float16*)alloc((size_t)CAPR * HHD * 2);

  // ---- chunk sizing: per-row bytes = xs 2048 + A 2048 + y0 2048 + H 4096
  //      + approx partials (32 slots x 16 B) 512 = 10752 ----
  size_t fixed = (size_t)(p - (char*)d_ws);
  size_t reserve = 2u << 20;
  size_t remain = ws_size > fixed + reserve ? ws_size - fixed - reserve : 0;
  int chunk = (int)(remain / 10752);
  chunk &= ~127;
  if (chunk < 128) chunk = 128;
  if (chunk > MTOT) chunk = MTOT;

  _Float16* xs_h = (_Float16*)alloc((size_t)chunk * 512 * 2);
  _Float16* xs_l = (_Float16*)alloc((size_t)chunk * 512 * 2);
  float*    Abuf = (float*)alloc((size_t)chunk * 512 * 4);
  _Float16* y0_h = (_Float16*)alloc((size_t)chunk * 512 * 2);
  _Float16* y0_l = (_Float16*)alloc((size_t)chunk * 512 * 2);
  _Float16* H_h  = (_Float16*)alloc((size_t)chunk * 1024 * 2);
  _Float16* H_l  = (_Float16*)alloc((size_t)chunk * 1024 * 2);
  float* pMa  = (float*)alloc((size_t)32 * chunk * 4);
  float* pM2a = (float*)alloc((size_t)32 * chunk * 4);
  float* pSa  = (float*)alloc((size_t)32 * chunk * 4);
  int*   pIa  = (int*)alloc((size_t)32 * chunk * 4);
  _Float16* y1_h = xs_h;   // alias: xs consumed by gemm1 before ln_dual writes
  _Float16* y1_l = xs_l;

  zero_cnt<<<2, 256, 0, stream>>>(cnt);
  prep_wvo_split<<<1024, 256, 0, stream>>>(vw, ow, wvo_h, wvo_l);
  prep_cvec<<<2, 256, 0, stream>>>(ow, vb, ob, cvec);
  prep_w1p_split<<<2048, 256, 0, stream>>>(w1, lng, w1p_h, w1p_l);
  prep_b1p<<<4, 256, 0, stream>>>(w1, lnb, b1, b1p);
  prep_w2_split<<<8192, 256, 0, stream>>>(w2, w2_h, w2_l);

  int citer = 0;
  for (int row0 = 0; row0 < MTOT; row0 += chunk, ++citer) {
    int rows = (MTOT - row0 < chunk) ? (MTOT - row0) : chunk;
    split_x<<<rows * 512 / 2048, 256, 0, stream>>>(X + (size_t)row0 * 512, xs_h, xs_l);
    gemm_split<0, 512, 512><<<dim3(rows / 128, 4), 256, 0, stream>>>(
        xs_h, xs_l, wvo_h, wvo_l, cvec, Abuf, nullptr, nullptr,
        nullptr, nullptr, nullptr, 0);
    ln_dual<<<rows / 4, 256, 0, stream>>>(Abuf, X + (size_t)row0 * 512, na,
                                          y0_h, y0_l, y1_h, y1_l);
    for (int s = 0; s < 2; ++s) {
      int* cp = cnt + citer * 2 + s;
      gemm_split<1, 512, 1024><<<dim3(rows / 128, 8), 256, 0, stream>>>(
          s == 0 ? y0_h : y1_h, s == 0 ? y0_l : y1_l, w1p_h, w1p_l, b1p,
          nullptr, H_h, H_l, nullptr, nullptr, nullptr, 0);
      gemm_approx<<<dim3(8, (rows / 128) * 2), 256, 0, stream>>>(
          H_h, w2_h, b2, pMa, pM2a, pSa, pIa, chunk);
      flag_k<<<(rows + 255) / 256, 256, 0, stream>>>(
          pMa, pM2a, pSa, pIa, chunk, rows,
          s == 0 ? map0 : map1, s == 0 ? iap0 : iap1, row0, list, cp);
      gather_k<<<CAPR, 128, 0, stream>>>(H_h, H_l, list, cp, Gh, Gl);
      gemm_split<2, 1024, 2048><<<dim3(32, 16), 256, 0, stream>>>(
          Gh, Gl, w2_h, w2_l, b2, nullptr, nullptr, nullptr,
          pMr, pIr, cp, CAPR);
      rescue_merge<<<CAPR / 256, 256, 0, stream>>>(
          pMr, pIr, list, cp, s == 0 ? iap0 : iap1, row0);
    }
  }
  finalize_k<<<MTOT / 256, 256, 0, stream>>>(map0, iap0, map1, iap1, out);
}